// Round 2
// baseline (1125.274 us; speedup 1.0000x reference)
//
#include <hip/hip_runtime.h>

// Content_SA: instance-norm -> f/g/h 1x1 convs -> attention(QK^T softmax, PV) -> o conv + residual.
// B=4, C=512, H=W=64 (N=4096).
// Precision strategy: energy[n,m] = xn(n)^T M xn(m) + u[m] (+ query-const, cancels in softmax),
// M = f_w^T g_w computed fp32, all matmuls feeding the softmax done in split-bf16 (hi+lo, 3 products)
// so logits are fp32-grade. P/V/o path is plain bf16 (relative-error-only).

typedef __bf16 bf16_t;
typedef __bf16 bf16x8 __attribute__((ext_vector_type(8)));
typedef float f32x4 __attribute__((ext_vector_type(4)));

#define LOG2E 1.44269504088896340736f

__device__ __forceinline__ void gload16(const void* g, void* l) {
  __builtin_amdgcn_global_load_lds(
      (const __attribute__((address_space(1))) void*)g,
      (__attribute__((address_space(3))) void*)l, 16, 0, 0);
}

// ---------------- instance-norm statistics: one block per (b,c) row ----------------
__global__ void __launch_bounds__(256) stats_k(const float* __restrict__ x,
                                               float* __restrict__ mu,
                                               float* __restrict__ rs) {
  const int bc = blockIdx.x;
  const float4* row = (const float4*)(x + (size_t)bc * 4096);
  float s = 0.f, ss = 0.f;
  for (int i = threadIdx.x; i < 1024; i += 256) {
    float4 v = row[i];
    s += v.x + v.y + v.z + v.w;
    ss += v.x * v.x + v.y * v.y + v.z * v.z + v.w * v.w;
  }
#pragma unroll
  for (int o = 32; o >= 1; o >>= 1) {
    s += __shfl_down(s, o);
    ss += __shfl_down(ss, o);
  }
  __shared__ float as_[4], ass_[4];
  const int w = threadIdx.x >> 6;
  if ((threadIdx.x & 63) == 0) { as_[w] = s; ass_[w] = ss; }
  __syncthreads();
  if (threadIdx.x == 0) {
    float st = as_[0] + as_[1] + as_[2] + as_[3];
    float sst = ass_[0] + ass_[1] + ass_[2] + ass_[3];
    float m = st * (1.f / 4096.f);
    float var = sst * (1.f / 4096.f) - m * m;
    mu[bc] = m;
    rs[bc] = rsqrtf(var + 1e-5f);
  }
}

// ---------------- cast h_w, o_w fp32 -> bf16 ----------------
__global__ void __launch_bounds__(256) wcast2_k(const float* __restrict__ a,
                                                const float* __restrict__ b,
                                                bf16_t* __restrict__ dst) {
  const int i = blockIdx.x * 256 + threadIdx.x;  // 131072 threads, one float4 each
  const int which = i >> 16;
  const int off = i & 65535;
  const float* s = which ? b : a;
  const float4 v = ((const float4*)s)[off];
  alignas(8) bf16_t r[4];
  r[0] = (bf16_t)v.x; r[1] = (bf16_t)v.y; r[2] = (bf16_t)v.z; r[3] = (bf16_t)v.w;
  *(uint2*)(dst + ((size_t)which << 18) + (size_t)off * 4) = *(const uint2*)r;
}

// ---------------- Mt[j][i] = sum_c f_w[c][i]*g_w[c][j], fp32, split to bf16 hi/lo ----------------
__global__ void __launch_bounds__(256) mt_k(const float* __restrict__ fw,
                                            const float* __restrict__ gw,
                                            bf16_t* __restrict__ Mth,
                                            bf16_t* __restrict__ Mtl) {
  __shared__ float Fs[32][64];
  __shared__ float Gs[32][64];
  const int t = threadIdx.x;
  const int it = blockIdx.x, jt = blockIdx.y;  // 8 x 8 tiles of 64
  float acc[16];
#pragma unroll
  for (int i = 0; i < 16; ++i) acc[i] = 0.f;
  const int jl = t >> 2, ib = (t & 3) * 16;
  const int lr = t >> 4, lc4 = (t & 15) * 4;
  for (int cc = 0; cc < 16; ++cc) {
    __syncthreads();
#pragma unroll
    for (int rep = 0; rep < 2; ++rep) {
      const int r = lr + rep * 16;
      *(float4*)&Fs[r][lc4] = *(const float4*)(fw + (size_t)(cc * 32 + r) * 512 + it * 64 + lc4);
      *(float4*)&Gs[r][lc4] = *(const float4*)(gw + (size_t)(cc * 32 + r) * 512 + jt * 64 + lc4);
    }
    __syncthreads();
#pragma unroll
    for (int c = 0; c < 32; ++c) {
      const float gv = Gs[c][jl];
#pragma unroll
      for (int ii = 0; ii < 16; ++ii) acc[ii] += gv * Fs[c][ib + ii];
    }
  }
  alignas(16) bf16_t hi[16], lo[16];
#pragma unroll
  for (int ii = 0; ii < 16; ++ii) {
    hi[ii] = (bf16_t)acc[ii];
    lo[ii] = (bf16_t)(acc[ii] - (float)hi[ii]);
  }
  const size_t o = (size_t)(jt * 64 + jl) * 512 + it * 64 + ib;
  *(uint4*)(Mth + o) = *(const uint4*)hi;
  *(uint4*)(Mth + o + 8) = *(const uint4*)(hi + 8);
  *(uint4*)(Mtl + o) = *(const uint4*)lo;
  *(uint4*)(Mtl + o + 8) = *(const uint4*)(lo + 8);
}

// ---------------- v[j] = sum_c g_w[c][j] * f_b[c] ----------------
__global__ void __launch_bounds__(256) v_k(const float* __restrict__ gw,
                                           const float* __restrict__ fb,
                                           float* __restrict__ v) {
  const int j = blockIdx.x * 256 + threadIdx.x;  // grid 2
  float s = 0.f;
  for (int c = 0; c < 512; ++c) s += gw[(size_t)c * 512 + j] * fb[c];
  v[j] = s;
}

// ---------------- u[b][m] = v . xn(m) (key-side bias term) ----------------
__global__ void __launch_bounds__(256) u_k(const float* __restrict__ v,
                                           const bf16_t* __restrict__ xnh,
                                           const bf16_t* __restrict__ xnl,
                                           float* __restrict__ u) {
  const int w = threadIdx.x >> 6, lane = threadIdx.x & 63;
  const int m = blockIdx.x * 4 + w;  // grid (1024, B)
  const int b = blockIdx.y;
  const size_t o = ((size_t)b * 4096 + m) * 512 + lane * 8;
  const bf16x8 vh = *(const bf16x8*)(xnh + o);
  const bf16x8 vl = *(const bf16x8*)(xnl + o);
  const float4 v0 = *(const float4*)(v + lane * 8);
  const float4 v1 = *(const float4*)(v + lane * 8 + 4);
  float s = 0.f;
  const float* vp = &v0.x;
#pragma unroll
  for (int e = 0; e < 4; ++e) s += ((float)vh[e] + (float)vl[e]) * vp[e];
  const float* vq = &v1.x;
#pragma unroll
  for (int e = 0; e < 4; ++e) s += ((float)vh[4 + e] + (float)vl[4 + e]) * vq[e];
#pragma unroll
  for (int o2 = 32; o2 >= 1; o2 >>= 1) s += __shfl_down(s, o2);
  if (lane == 0) u[(size_t)b * 4096 + m] = s;
}

// ---------------- normalize + transpose + split-cast: x[b][c][n] -> xnh/xnl/xc[b][n][c] ----------------
__global__ void __launch_bounds__(256) normt_k(const float* __restrict__ x,
                                               const float* __restrict__ mu,
                                               const float* __restrict__ rs,
                                               bf16_t* __restrict__ xnh,
                                               bf16_t* __restrict__ xnl,
                                               bf16_t* __restrict__ xc) {
  __shared__ float tile[64][65];
  const int t = threadIdx.x;
  const int nt = blockIdx.x, ct = blockIdx.y, b = blockIdx.z;
  const float* src = x + ((size_t)b * 512 + ct * 64) * 4096 + nt * 64;
  {
    const int r = t >> 4, cq = (t & 15) * 4;
#pragma unroll
    for (int it = 0; it < 4; ++it) {
      const int rr = r + it * 16;
      const float4 v = *(const float4*)(src + (size_t)rr * 4096 + cq);
      tile[rr][cq] = v.x; tile[rr][cq + 1] = v.y;
      tile[rr][cq + 2] = v.z; tile[rr][cq + 3] = v.w;
    }
  }
  __syncthreads();
  const int n = t & 63, ch = t >> 6;
  alignas(16) bf16_t vh[16], vl[16], vc[16];
#pragma unroll
  for (int i = 0; i < 16; ++i) {
    const int c = ch * 16 + i;
    const float v = tile[c][n];
    const int gc = b * 512 + ct * 64 + c;
    vc[i] = (bf16_t)v;
    const float vn = (v - mu[gc]) * rs[gc];
    const bf16_t h = (bf16_t)vn;
    vh[i] = h;
    vl[i] = (bf16_t)(vn - (float)h);
  }
  const size_t o = ((size_t)b * 4096 + nt * 64 + n) * 512 + ct * 64 + ch * 16;
  *(uint4*)(xnh + o) = *(const uint4*)vh;
  *(uint4*)(xnh + o + 8) = *(const uint4*)(vh + 8);
  *(uint4*)(xnl + o) = *(const uint4*)vl;
  *(uint4*)(xnl + o + 8) = *(const uint4*)(vl + 8);
  *(uint4*)(xc + o) = *(const uint4*)vc;
  *(uint4*)(xc + o + 8) = *(const uint4*)(vc + 8);
}

// ---------------- bf16 tile transpose: [b][C][N] -> [b][N][C] ----------------
__global__ void __launch_bounds__(256) tbf16_k(const bf16_t* __restrict__ src,
                                               bf16_t* __restrict__ dst) {
  __shared__ alignas(16) bf16_t tile[64][72];
  const int t = threadIdx.x;
  const int nt = blockIdx.x, ct = blockIdx.y, b = blockIdx.z;
  const bf16_t* s = src + ((size_t)b * 512 + ct * 64) * 4096 + nt * 64;
  {
    const int r = t >> 3, cq = (t & 7) * 8;
#pragma unroll
    for (int it = 0; it < 2; ++it) {
      const int rr = r + it * 32;
      *(bf16x8*)&tile[rr][cq] = *(const bf16x8*)(s + (size_t)rr * 4096 + cq);
    }
  }
  __syncthreads();
  const int n = t & 63, ch = t >> 6;
  alignas(16) bf16_t v[16];
#pragma unroll
  for (int i = 0; i < 16; ++i) v[i] = tile[ch * 16 + i][n];
  const size_t o = ((size_t)b * 4096 + nt * 64 + n) * 512 + ct * 64 + ch * 16;
  *(uint4*)(dst + o) = *(const uint4*)v;
  *(uint4*)(dst + o + 8) = *(const uint4*)(v + 8);
}

// ---------------- GEMM: C[m][n] = sum_k A[m][k]*Bt[n][k] (+biasM/+biasN/+resid), K=512 ----------------
template <typename OT, int BIAS, bool RESID>
__global__ void __launch_bounds__(256) gemm_k(const bf16_t* __restrict__ A,
                                              const bf16_t* __restrict__ Bt,
                                              OT* __restrict__ C,
                                              const float* __restrict__ biasM,
                                              const float* __restrict__ biasN,
                                              const float* __restrict__ resid,
                                              long sAb, long sBb, long sCb, int ldC) {
  __shared__ alignas(16) bf16_t As[128 * 64];
  __shared__ alignas(16) bf16_t Bs[128 * 64];
  const int t = threadIdx.x;
  const int lane = t & 63;
  const int w = t >> 6;
  const int wr = w >> 1, wc = w & 1;
  const int l15 = lane & 15, lg = lane >> 4;
  const int b = blockIdx.z;
  const int m0 = blockIdx.y * 128, n0 = blockIdx.x * 128;
  const bf16_t* Ab = A + (size_t)sAb * b + (size_t)m0 * 512;
  const bf16_t* Bb = Bt + (size_t)sBb * b + (size_t)n0 * 512;

  const f32x4 z4 = {0.f, 0.f, 0.f, 0.f};
  f32x4 acc[4][4];
#pragma unroll
  for (int i = 0; i < 4; ++i)
#pragma unroll
    for (int j = 0; j < 4; ++j) acc[i][j] = z4;

  const int srow = t >> 3;
  const int slot = t & 7;
  for (int ks = 0; ks < 8; ++ks) {
    __syncthreads();
#pragma unroll
    for (int r = 0; r < 4; ++r) {
      const int rr = r * 32 + srow;
      gload16(Ab + (size_t)rr * 512 + ks * 64 + ((slot ^ (rr & 7)) * 8),
              (char*)As + r * 4096 + w * 1024);
      gload16(Bb + (size_t)rr * 512 + ks * 64 + ((slot ^ (rr & 7)) * 8),
              (char*)Bs + r * 4096 + w * 1024);
    }
    __syncthreads();
#pragma unroll
    for (int kk = 0; kk < 2; ++kk) {
      bf16x8 af[4], bfr[4];
#pragma unroll
      for (int i = 0; i < 4; ++i) {
        const int ra = wr * 64 + i * 16 + l15;
        af[i] = *(const bf16x8*)((const char*)As + ra * 128 + (((kk * 4 + lg) ^ (ra & 7)) * 16));
        const int rb = wc * 64 + i * 16 + l15;
        bfr[i] = *(const bf16x8*)((const char*)Bs + rb * 128 + (((kk * 4 + lg) ^ (rb & 7)) * 16));
      }
#pragma unroll
      for (int i = 0; i < 4; ++i)
#pragma unroll
        for (int j = 0; j < 4; ++j)
          acc[i][j] = __builtin_amdgcn_mfma_f32_16x16x32_bf16(af[i], bfr[j], acc[i][j], 0, 0, 0);
    }
  }
  OT* Cb = C + (size_t)sCb * b;
#pragma unroll
  for (int i = 0; i < 4; ++i) {
#pragma unroll
    for (int j = 0; j < 4; ++j) {
      const int n = n0 + wc * 64 + j * 16 + l15;
      float bn = 0.f;
      if (BIAS == 2) bn = biasN[n];
#pragma unroll
      for (int r = 0; r < 4; ++r) {
        const int m = m0 + wr * 64 + i * 16 + lg * 4 + r;
        float v = acc[i][j][r] + bn;
        if (BIAS == 1) v += biasM[m];
        if (RESID) v += resid[(size_t)sCb * b + (size_t)m * ldC + n];
        Cb[(size_t)m * ldC + n] = (OT)v;
      }
    }
  }
}

// ---------------- split GEMM: Z = (Ah+Al).(Bh+Bl)^T via 3 products, split output ----------------
__global__ void __launch_bounds__(256) gemm3_k(const bf16_t* __restrict__ Ah,
                                               const bf16_t* __restrict__ Al,
                                               const bf16_t* __restrict__ Bh,
                                               const bf16_t* __restrict__ Bl,
                                               bf16_t* __restrict__ Ch,
                                               bf16_t* __restrict__ Cl,
                                               long sAb, long sCb) {
  __shared__ alignas(16) bf16_t Ash[128 * 64];
  __shared__ alignas(16) bf16_t Asl[128 * 64];
  __shared__ alignas(16) bf16_t Bsh[128 * 64];
  __shared__ alignas(16) bf16_t Bsl[128 * 64];
  const int t = threadIdx.x;
  const int lane = t & 63;
  const int w = t >> 6;
  const int wr = w >> 1, wc = w & 1;
  const int l15 = lane & 15, lg = lane >> 4;
  const int b = blockIdx.z;
  const int m0 = blockIdx.y * 128, n0 = blockIdx.x * 128;
  const bf16_t* Ahb = Ah + (size_t)sAb * b + (size_t)m0 * 512;
  const bf16_t* Alb = Al + (size_t)sAb * b + (size_t)m0 * 512;
  const bf16_t* Bhb = Bh + (size_t)n0 * 512;
  const bf16_t* Blb = Bl + (size_t)n0 * 512;

  const f32x4 z4 = {0.f, 0.f, 0.f, 0.f};
  f32x4 acc[4][4];
#pragma unroll
  for (int i = 0; i < 4; ++i)
#pragma unroll
    for (int j = 0; j < 4; ++j) acc[i][j] = z4;

  const int srow = t >> 3;
  const int slot = t & 7;
  for (int ks = 0; ks < 8; ++ks) {
    __syncthreads();
#pragma unroll
    for (int r = 0; r < 4; ++r) {
      const int rr = r * 32 + srow;
      const size_t go = (size_t)rr * 512 + ks * 64 + ((slot ^ (rr & 7)) * 8);
      gload16(Ahb + go, (char*)Ash + r * 4096 + w * 1024);
      gload16(Alb + go, (char*)Asl + r * 4096 + w * 1024);
      gload16(Bhb + go, (char*)Bsh + r * 4096 + w * 1024);
      gload16(Blb + go, (char*)Bsl + r * 4096 + w * 1024);
    }
    __syncthreads();
#pragma unroll
    for (int kk = 0; kk < 2; ++kk) {
      bf16x8 ah[4], al[4], bh[4], bl[4];
#pragma unroll
      for (int i = 0; i < 4; ++i) {
        const int ra = wr * 64 + i * 16 + l15;
        const int sa = (((kk * 4 + lg) ^ (ra & 7)) * 16);
        ah[i] = *(const bf16x8*)((const char*)Ash + ra * 128 + sa);
        al[i] = *(const bf16x8*)((const char*)Asl + ra * 128 + sa);
        const int rb = wc * 64 + i * 16 + l15;
        const int sb = (((kk * 4 + lg) ^ (rb & 7)) * 16);
        bh[i] = *(const bf16x8*)((const char*)Bsh + rb * 128 + sb);
        bl[i] = *(const bf16x8*)((const char*)Bsl + rb * 128 + sb);
      }
#pragma unroll
      for (int i = 0; i < 4; ++i)
#pragma unroll
        for (int j = 0; j < 4; ++j) {
          acc[i][j] = __builtin_amdgcn_mfma_f32_16x16x32_bf16(ah[i], bh[j], acc[i][j], 0, 0, 0);
          acc[i][j] = __builtin_amdgcn_mfma_f32_16x16x32_bf16(ah[i], bl[j], acc[i][j], 0, 0, 0);
          acc[i][j] = __builtin_amdgcn_mfma_f32_16x16x32_bf16(al[i], bh[j], acc[i][j], 0, 0, 0);
        }
    }
  }
  bf16_t* Chb = Ch + (size_t)sCb * b;
  bf16_t* Clb = Cl + (size_t)sCb * b;
#pragma unroll
  for (int i = 0; i < 4; ++i) {
#pragma unroll
    for (int j = 0; j < 4; ++j) {
      const int n = n0 + wc * 64 + j * 16 + l15;
#pragma unroll
      for (int r = 0; r < 4; ++r) {
        const int m = m0 + wr * 64 + i * 16 + lg * 4 + r;
        const float v = acc[i][j][r];
        const bf16_t hi = (bf16_t)v;
        Chb[(size_t)m * 512 + n] = hi;
        Clb[(size_t)m * 512 + n] = (bf16_t)(v - (float)hi);
      }
    }
  }
}

// ---------------- flash attention with split-precision logits ----------------
// Q=(Zh+Zl)[b][q][c], K=(Xh+Xl)[b][k][c], +u[b][k]; V=Hv[b][c][k]; out Oat[b][c][q].
__global__ void __launch_bounds__(256) flash_k(const bf16_t* __restrict__ Zh,
                                               const bf16_t* __restrict__ Zl,
                                               const bf16_t* __restrict__ Xh,
                                               const bf16_t* __restrict__ Xl,
                                               const float* __restrict__ u,
                                               const bf16_t* __restrict__ Hv,
                                               bf16_t* __restrict__ Oat) {
  __shared__ alignas(16) bf16_t KldsH[64 * 256];  // 32KB (half of channels), swizzled
  __shared__ alignas(16) bf16_t KldsL[64 * 256];  // 32KB
  __shared__ alignas(16) bf16_t Plds[32 * 64];    // 4KB
  __shared__ float redm[2][2][16];
  __shared__ float reds[2][2][16];
  __shared__ float alds[32];
  __shared__ float llds[32];

  const int t = threadIdx.x;
  const int lane = t & 63;
  const int w = t >> 6;
  const int wq = w & 1, wk = w >> 1;
  const int l15 = lane & 15, lg = lane >> 4;
  const int b = blockIdx.y;
  const int q0 = blockIdx.x * 32;

  // Q fragments in registers: q = q0+16*wq+l15, c = cc*32 + lg*8 + [0..8)
  bf16x8 qh[16], ql[16];
  {
    const size_t qo = ((size_t)b * 4096 + q0 + 16 * wq + l15) * 512 + lg * 8;
#pragma unroll
    for (int cc = 0; cc < 16; ++cc) {
      qh[cc] = *(const bf16x8*)(Zh + qo + cc * 32);
      ql[cc] = *(const bf16x8*)(Zl + qo + cc * 32);
    }
  }

  const f32x4 z4 = {0.f, 0.f, 0.f, 0.f};
  f32x4 oacc[8][2];
#pragma unroll
  for (int i = 0; i < 8; ++i) { oacc[i][0] = z4; oacc[i][1] = z4; }
  float m_run = -3.0e38f, l_run = 0.f;

  const bf16_t* KbH = Xh + (size_t)b * 4096 * 512;
  const bf16_t* KbL = Xl + (size_t)b * 4096 * 512;
  const bf16_t* Vb = Hv + (size_t)b * 512 * 4096;
  const float* ub = u + (size_t)b * 4096;

  for (int kt = 0; kt < 64; ++kt) {
    const int k0 = kt * 64;
    f32x4 sacc[2] = {z4, z4};
#pragma unroll
    for (int ch = 0; ch < 2; ++ch) {
      __syncthreads();
      {  // stage 64 keys x 256 channels, hi+lo (64KB total) ; source pre-swizzled
        const int srow = t >> 5;
        const int slot = t & 31;
#pragma unroll
        for (int r = 0; r < 8; ++r) {
          const int row = r * 8 + srow;
          const size_t go = (size_t)(k0 + row) * 512 + ch * 256 + ((slot ^ (row & 7)) * 8);
          gload16(KbH + go, (char*)KldsH + r * 4096 + w * 1024);
          gload16(KbL + go, (char*)KldsL + r * 4096 + w * 1024);
        }
      }
      __syncthreads();
#pragma unroll
      for (int c8 = 0; c8 < 8; ++c8) {
        const bf16x8 qhf = qh[ch * 8 + c8];
        const bf16x8 qlf = ql[ch * 8 + c8];
#pragma unroll
        for (int mf = 0; mf < 2; ++mf) {
          const int key = 32 * wk + 16 * mf + l15;
          const int so = ((c8 * 4 + lg) ^ (key & 7)) * 16;
          const bf16x8 kh = *(const bf16x8*)((const char*)KldsH + key * 512 + so);
          const bf16x8 kl = *(const bf16x8*)((const char*)KldsL + key * 512 + so);
          sacc[mf] = __builtin_amdgcn_mfma_f32_16x16x32_bf16(kh, qhf, sacc[mf], 0, 0, 0);
          sacc[mf] = __builtin_amdgcn_mfma_f32_16x16x32_bf16(kh, qlf, sacc[mf], 0, 0, 0);
          sacc[mf] = __builtin_amdgcn_mfma_f32_16x16x32_bf16(kl, qhf, sacc[mf], 0, 0, 0);
        }
      }
    }
    // key-side bias u
#pragma unroll
    for (int mf = 0; mf < 2; ++mf)
#pragma unroll
      for (int j = 0; j < 4; ++j)
        sacc[mf][j] += ub[k0 + 32 * wk + 16 * mf + 4 * lg + j];
    // ---- online softmax (q = 16*wq + l15 is lane-local in cols) ----
    float pm = -3.0e38f;
#pragma unroll
    for (int mf = 0; mf < 2; ++mf)
#pragma unroll
      for (int j = 0; j < 4; ++j) pm = fmaxf(pm, sacc[mf][j]);
    pm = fmaxf(pm, __shfl_xor(pm, 16));
    pm = fmaxf(pm, __shfl_xor(pm, 32));
    if (lane < 16) redm[wq][wk][lane] = pm;
    __syncthreads();
    const float m_tile = fmaxf(pm, redm[wq][wk ^ 1][l15]);
    const float m_new = fmaxf(m_run, m_tile);
    const float alpha = exp2f((m_run - m_new) * LOG2E);
    float ps = 0.f;
    const int qrow = 16 * wq + l15;
#pragma unroll
    for (int mf = 0; mf < 2; ++mf)
#pragma unroll
      for (int j = 0; j < 4; ++j) {
        const float p = exp2f((sacc[mf][j] - m_new) * LOG2E);
        ps += p;
        const int k = 32 * wk + 16 * mf + 4 * lg + j;
        *(bf16_t*)((char*)Plds + qrow * 128 + ((k * 2) ^ ((qrow & 7) << 4))) = (bf16_t)p;
      }
    ps += __shfl_xor(ps, 16);
    ps += __shfl_xor(ps, 32);
    if (lane < 16) {
      reds[wq][wk][lane] = ps;
      if (wk == 0) alds[16 * wq + lane] = alpha;
    }
    __syncthreads();
    const float s_tile = reds[wq][0][l15] + reds[wq][1][l15];
    l_run = l_run * alpha + s_tile;
    m_run = m_new;
    // ---- PV: oacc[c][q] += V[c][k] * P[q][k] ----
    const float a0 = alds[l15];
    const float a1 = alds[l15 + 16];
#pragma unroll
    for (int mf = 0; mf < 8; ++mf) { oacc[mf][0] *= a0; oacc[mf][1] *= a1; }
#pragma unroll
    for (int kk = 0; kk < 2; ++kk) {
      const int q1 = l15, q2 = l15 + 16;
      bf16x8 bp0 = *(const bf16x8*)((const char*)Plds + q1 * 128 +
                                    (((kk * 32 + lg * 8) * 2) ^ ((q1 & 7) << 4)));
      bf16x8 bp1 = *(const bf16x8*)((const char*)Plds + q2 * 128 +
                                    (((kk * 32 + lg * 8) * 2) ^ ((q2 & 7) << 4)));
#pragma unroll
      for (int mf = 0; mf < 8; ++mf) {
        const int c = 128 * w + 16 * mf + l15;
        bf16x8 vf = *(const bf16x8*)(Vb + (size_t)c * 4096 + k0 + kk * 32 + lg * 8);
        oacc[mf][0] = __builtin_amdgcn_mfma_f32_16x16x32_bf16(vf, bp0, oacc[mf][0], 0, 0, 0);
        oacc[mf][1] = __builtin_amdgcn_mfma_f32_16x16x32_bf16(vf, bp1, oacc[mf][1], 0, 0, 0);
      }
    }
  }
  // ---- epilogue ----
  if (wk == 0 && lane < 16) llds[16 * wq + lane] = l_run;
  __syncthreads();
  const float inv0 = 1.f / llds[l15];
  const float inv1 = 1.f / llds[l15 + 16];
#pragma unroll
  for (int mf = 0; mf < 8; ++mf)
#pragma unroll
    for (int j = 0; j < 4; ++j) {
      const int c = 128 * w + 16 * mf + 4 * lg + j;
      const size_t base = ((size_t)b * 512 + c) * 4096 + q0;
      Oat[base + l15] = (bf16_t)(oacc[mf][0][j] * inv0);
      Oat[base + l15 + 16] = (bf16_t)(oacc[mf][1][j] * inv1);
    }
}

// ---------------- host launch ----------------
extern "C" void kernel_launch(void* const* d_in, const int* in_sizes, int n_in,
                              void* d_out, int out_size, void* d_ws, size_t ws_size,
                              hipStream_t stream) {
  const float* x = (const float*)d_in[0];
  const float* fw = (const float*)d_in[1];
  const float* fb = (const float*)d_in[2];
  const float* gw = (const float*)d_in[3];
  const float* gb = (const float*)d_in[4];
  const float* hw = (const float*)d_in[5];
  const float* hb = (const float*)d_in[6];
  const float* ow = (const float*)d_in[7];
  const float* ob = (const float*)d_in[8];
  float* out = (float*)d_out;
  (void)gb;

  const size_t BIG = (size_t)4 * 4096 * 512 * sizeof(bf16_t);  // 16.78MB
  char* p = (char*)d_ws;
  float* mu = (float*)p; p += 2048 * sizeof(float);
  float* rs = (float*)p; p += 2048 * sizeof(float);
  float* vv = (float*)p; p += 512 * sizeof(float);
  float* uu = (float*)p; p += (size_t)4 * 4096 * sizeof(float);
  bf16_t* w2 = (bf16_t*)p; p += (size_t)2 * 512 * 512 * sizeof(bf16_t);
  bf16_t* Mth = (bf16_t*)p; p += (size_t)512 * 512 * sizeof(bf16_t);
  bf16_t* Mtl = (bf16_t*)p; p += (size_t)512 * 512 * sizeof(bf16_t);
  bf16_t* xnh = (bf16_t*)p; p += BIG;
  bf16_t* xnl = (bf16_t*)p; p += BIG;
  bf16_t* xc = (bf16_t*)p; p += BIG;
  bf16_t* Zh = (bf16_t*)p; p += BIG;
  bf16_t* Zl = (bf16_t*)p; p += BIG;
  bf16_t* Hv = (bf16_t*)p; p += BIG;  // total ~103MB
  bf16_t* Oat = xc;     // alias: xc dead after Hv gemm
  bf16_t* Oat_t = xnh;  // alias: xnh dead after flash

  bf16_t* whb = w2;
  bf16_t* wob = w2 + 262144;

  const long sD = (long)4096 * 512;

  stats_k<<<2048, 256, 0, stream>>>(x, mu, rs);
  wcast2_k<<<512, 256, 0, stream>>>(hw, ow, w2);
  mt_k<<<dim3(8, 8), 256, 0, stream>>>(fw, gw, Mth, Mtl);
  v_k<<<2, 256, 0, stream>>>(gw, fb, vv);
  normt_k<<<dim3(64, 8, 4), 256, 0, stream>>>(x, mu, rs, xnh, xnl, xc);
  u_k<<<dim3(1024, 4), 256, 0, stream>>>(vv, xnh, xnl, uu);
  // Z[b][n][j] = sum_i xn[n][i] * Mt[j][i]  (split 3-product)
  gemm3_k<<<dim3(4, 32, 4), 256, 0, stream>>>(xnh, xnl, Mth, Mtl, Zh, Zl, sD, sD);
  // Hv[b][c][n] = h_w . xc  (+h_b over c)
  gemm_k<bf16_t, 1, false><<<dim3(32, 4, 4), 256, 0, stream>>>(
      whb, xc, Hv, hb, nullptr, nullptr, 0, sD, sD, 4096);
  // attention
  flash_k<<<dim3(128, 4), 256, 0, stream>>>(Zh, Zl, xnh, xnl, uu, Hv, Oat);
  // transpose attention output to [b][n][c]
  tbf16_k<<<dim3(64, 8, 4), 256, 0, stream>>>(Oat, Oat_t);
  // out[b][o][n] = o_w . Oat_t^T (+o_b over o) + residual, fp32
  gemm_k<float, 1, true><<<dim3(32, 4, 4), 256, 0, stream>>>(
      wob, Oat_t, out, ob, nullptr, x, 0, sD, sD, 4096);

  (void)in_sizes; (void)n_in; (void)out_size; (void)ws_size;
}

// Round 3
// 1039.170 us; speedup vs baseline: 1.0829x; 1.0829x over previous
//
#include <hip/hip_runtime.h>

// Content_SA: instance-norm -> f/g/h 1x1 convs -> attention(QK^T softmax, PV) -> o conv + residual.
// B=4, C=512, H=W=64 (N=4096).
// Precision: energy[n,m] = xn(n)^T M xn(m) + u[m] (+ query-const, cancels in softmax),
// M = f_w^T g_w fp32; softmax-feeding matmuls in split-bf16 (hi+lo, 3 products) -> fp32-grade logits.
// Flash v2: q=64/block, 8 waves (4 wq x 2 wk), stage-ahead double-buffered K staging (T3 recipe),
// u in LDS, packed b64 P-writes, XCD-aware block swizzle.

typedef __bf16 bf16_t;
typedef __bf16 bf16x8 __attribute__((ext_vector_type(8)));
typedef float f32x4 __attribute__((ext_vector_type(4)));

#define LOG2E 1.44269504088896340736f

__device__ __forceinline__ void gload16(const void* g, void* l) {
  __builtin_amdgcn_global_load_lds(
      (const __attribute__((address_space(1))) void*)g,
      (__attribute__((address_space(3))) void*)l, 16, 0, 0);
}

// ---------------- instance-norm statistics ----------------
__global__ void __launch_bounds__(256) stats_k(const float* __restrict__ x,
                                               float* __restrict__ mu,
                                               float* __restrict__ rs) {
  const int bc = blockIdx.x;
  const float4* row = (const float4*)(x + (size_t)bc * 4096);
  float s = 0.f, ss = 0.f;
  for (int i = threadIdx.x; i < 1024; i += 256) {
    float4 v = row[i];
    s += v.x + v.y + v.z + v.w;
    ss += v.x * v.x + v.y * v.y + v.z * v.z + v.w * v.w;
  }
#pragma unroll
  for (int o = 32; o >= 1; o >>= 1) {
    s += __shfl_down(s, o);
    ss += __shfl_down(ss, o);
  }
  __shared__ float as_[4], ass_[4];
  const int w = threadIdx.x >> 6;
  if ((threadIdx.x & 63) == 0) { as_[w] = s; ass_[w] = ss; }
  __syncthreads();
  if (threadIdx.x == 0) {
    float st = as_[0] + as_[1] + as_[2] + as_[3];
    float sst = ass_[0] + ass_[1] + ass_[2] + ass_[3];
    float m = st * (1.f / 4096.f);
    float var = sst * (1.f / 4096.f) - m * m;
    mu[bc] = m;
    rs[bc] = rsqrtf(var + 1e-5f);
  }
}

// ---------------- cast h_w, o_w fp32 -> bf16 ----------------
__global__ void __launch_bounds__(256) wcast2_k(const float* __restrict__ a,
                                                const float* __restrict__ b,
                                                bf16_t* __restrict__ dst) {
  const int i = blockIdx.x * 256 + threadIdx.x;
  const int which = i >> 16;
  const int off = i & 65535;
  const float* s = which ? b : a;
  const float4 v = ((const float4*)s)[off];
  alignas(8) bf16_t r[4];
  r[0] = (bf16_t)v.x; r[1] = (bf16_t)v.y; r[2] = (bf16_t)v.z; r[3] = (bf16_t)v.w;
  *(uint2*)(dst + ((size_t)which << 18) + (size_t)off * 4) = *(const uint2*)r;
}

// ---------------- Mt[j][i] = sum_c f_w[c][i]*g_w[c][j], fp32, split bf16 hi/lo ----------------
__global__ void __launch_bounds__(256) mt_k(const float* __restrict__ fw,
                                            const float* __restrict__ gw,
                                            bf16_t* __restrict__ Mth,
                                            bf16_t* __restrict__ Mtl) {
  __shared__ float Fs[32][64];
  __shared__ float Gs[32][64];
  const int t = threadIdx.x;
  const int it = blockIdx.x, jt = blockIdx.y;
  float acc[16];
#pragma unroll
  for (int i = 0; i < 16; ++i) acc[i] = 0.f;
  const int jl = t >> 2, ib = (t & 3) * 16;
  const int lr = t >> 4, lc4 = (t & 15) * 4;
  for (int cc = 0; cc < 16; ++cc) {
    __syncthreads();
#pragma unroll
    for (int rep = 0; rep < 2; ++rep) {
      const int r = lr + rep * 16;
      *(float4*)&Fs[r][lc4] = *(const float4*)(fw + (size_t)(cc * 32 + r) * 512 + it * 64 + lc4);
      *(float4*)&Gs[r][lc4] = *(const float4*)(gw + (size_t)(cc * 32 + r) * 512 + jt * 64 + lc4);
    }
    __syncthreads();
#pragma unroll
    for (int c = 0; c < 32; ++c) {
      const float gv = Gs[c][jl];
#pragma unroll
      for (int ii = 0; ii < 16; ++ii) acc[ii] += gv * Fs[c][ib + ii];
    }
  }
  alignas(16) bf16_t hi[16], lo[16];
#pragma unroll
  for (int ii = 0; ii < 16; ++ii) {
    hi[ii] = (bf16_t)acc[ii];
    lo[ii] = (bf16_t)(acc[ii] - (float)hi[ii]);
  }
  const size_t o = (size_t)(jt * 64 + jl) * 512 + it * 64 + ib;
  *(uint4*)(Mth + o) = *(const uint4*)hi;
  *(uint4*)(Mth + o + 8) = *(const uint4*)(hi + 8);
  *(uint4*)(Mtl + o) = *(const uint4*)lo;
  *(uint4*)(Mtl + o + 8) = *(const uint4*)(lo + 8);
}

// ---------------- v[j] = sum_c g_w[c][j] * f_b[c] ----------------
__global__ void __launch_bounds__(256) v_k(const float* __restrict__ gw,
                                           const float* __restrict__ fb,
                                           float* __restrict__ v) {
  const int j = blockIdx.x * 256 + threadIdx.x;
  float s = 0.f;
  for (int c = 0; c < 512; ++c) s += gw[(size_t)c * 512 + j] * fb[c];
  v[j] = s;
}

// ---------------- u[b][m] = v . xn(m) ----------------
__global__ void __launch_bounds__(256) u_k(const float* __restrict__ v,
                                           const bf16_t* __restrict__ xnh,
                                           const bf16_t* __restrict__ xnl,
                                           float* __restrict__ u) {
  const int w = threadIdx.x >> 6, lane = threadIdx.x & 63;
  const int m = blockIdx.x * 4 + w;
  const int b = blockIdx.y;
  const size_t o = ((size_t)b * 4096 + m) * 512 + lane * 8;
  const bf16x8 vh = *(const bf16x8*)(xnh + o);
  const bf16x8 vl = *(const bf16x8*)(xnl + o);
  const float4 v0 = *(const float4*)(v + lane * 8);
  const float4 v1 = *(const float4*)(v + lane * 8 + 4);
  float s = 0.f;
  const float* vp = &v0.x;
#pragma unroll
  for (int e = 0; e < 4; ++e) s += ((float)vh[e] + (float)vl[e]) * vp[e];
  const float* vq = &v1.x;
#pragma unroll
  for (int e = 0; e < 4; ++e) s += ((float)vh[4 + e] + (float)vl[4 + e]) * vq[e];
#pragma unroll
  for (int o2 = 32; o2 >= 1; o2 >>= 1) s += __shfl_down(s, o2);
  if (lane == 0) u[(size_t)b * 4096 + m] = s;
}

// ---------------- normalize + transpose + split-cast ----------------
__global__ void __launch_bounds__(256) normt_k(const float* __restrict__ x,
                                               const float* __restrict__ mu,
                                               const float* __restrict__ rs,
                                               bf16_t* __restrict__ xnh,
                                               bf16_t* __restrict__ xnl,
                                               bf16_t* __restrict__ xc) {
  __shared__ float tile[64][65];
  const int t = threadIdx.x;
  const int nt = blockIdx.x, ct = blockIdx.y, b = blockIdx.z;
  const float* src = x + ((size_t)b * 512 + ct * 64) * 4096 + nt * 64;
  {
    const int r = t >> 4, cq = (t & 15) * 4;
#pragma unroll
    for (int it = 0; it < 4; ++it) {
      const int rr = r + it * 16;
      const float4 v = *(const float4*)(src + (size_t)rr * 4096 + cq);
      tile[rr][cq] = v.x; tile[rr][cq + 1] = v.y;
      tile[rr][cq + 2] = v.z; tile[rr][cq + 3] = v.w;
    }
  }
  __syncthreads();
  const int n = t & 63, ch = t >> 6;
  alignas(16) bf16_t vh[16], vl[16], vc[16];
#pragma unroll
  for (int i = 0; i < 16; ++i) {
    const int c = ch * 16 + i;
    const float v = tile[c][n];
    const int gc = b * 512 + ct * 64 + c;
    vc[i] = (bf16_t)v;
    const float vn = (v - mu[gc]) * rs[gc];
    const bf16_t h = (bf16_t)vn;
    vh[i] = h;
    vl[i] = (bf16_t)(vn - (float)h);
  }
  const size_t o = ((size_t)b * 4096 + nt * 64 + n) * 512 + ct * 64 + ch * 16;
  *(uint4*)(xnh + o) = *(const uint4*)vh;
  *(uint4*)(xnh + o + 8) = *(const uint4*)(vh + 8);
  *(uint4*)(xnl + o) = *(const uint4*)vl;
  *(uint4*)(xnl + o + 8) = *(const uint4*)(vl + 8);
  *(uint4*)(xc + o) = *(const uint4*)vc;
  *(uint4*)(xc + o + 8) = *(const uint4*)(vc + 8);
}

// ---------------- bf16 tile transpose: [b][C][N] -> [b][N][C] ----------------
__global__ void __launch_bounds__(256) tbf16_k(const bf16_t* __restrict__ src,
                                               bf16_t* __restrict__ dst) {
  __shared__ alignas(16) bf16_t tile[64][72];
  const int t = threadIdx.x;
  const int nt = blockIdx.x, ct = blockIdx.y, b = blockIdx.z;
  const bf16_t* s = src + ((size_t)b * 512 + ct * 64) * 4096 + nt * 64;
  {
    const int r = t >> 3, cq = (t & 7) * 8;
#pragma unroll
    for (int it = 0; it < 2; ++it) {
      const int rr = r + it * 32;
      *(bf16x8*)&tile[rr][cq] = *(const bf16x8*)(s + (size_t)rr * 4096 + cq);
    }
  }
  __syncthreads();
  const int n = t & 63, ch = t >> 6;
  alignas(16) bf16_t v[16];
#pragma unroll
  for (int i = 0; i < 16; ++i) v[i] = tile[ch * 16 + i][n];
  const size_t o = ((size_t)b * 4096 + nt * 64 + n) * 512 + ct * 64 + ch * 16;
  *(uint4*)(dst + o) = *(const uint4*)v;
  *(uint4*)(dst + o + 8) = *(const uint4*)(v + 8);
}

// ---------------- GEMM (double-buffered, stage-ahead): C[m][n] = A[m][k].Bt[n][k], K=512 ----------------
template <typename OT, int BIAS, bool RESID>
__global__ void __launch_bounds__(256) gemm_k(const bf16_t* __restrict__ A,
                                              const bf16_t* __restrict__ Bt,
                                              OT* __restrict__ C,
                                              const float* __restrict__ biasM,
                                              const float* __restrict__ biasN,
                                              const float* __restrict__ resid,
                                              long sAb, long sBb, long sCb, int ldC) {
  __shared__ alignas(16) bf16_t As[2][128 * 64];
  __shared__ alignas(16) bf16_t Bs[2][128 * 64];
  const int t = threadIdx.x;
  const int lane = t & 63;
  const int w = t >> 6;
  const int wr = w >> 1, wc = w & 1;
  const int l15 = lane & 15, lg = lane >> 4;
  const int b = blockIdx.z;
  const int m0 = blockIdx.y * 128, n0 = blockIdx.x * 128;
  const bf16_t* Ab = A + (size_t)sAb * b + (size_t)m0 * 512;
  const bf16_t* Bb = Bt + (size_t)sBb * b + (size_t)n0 * 512;
  const int srow = t >> 3;
  const int slot = t & 7;

  auto gstage = [&](int pb_, int ks_) {
#pragma unroll
    for (int r_ = 0; r_ < 4; ++r_) {
      const int rr_ = r_ * 32 + srow;
      const size_t go_ = (size_t)rr_ * 512 + ks_ * 64 + ((slot ^ (rr_ & 7)) * 8);
      gload16(Ab + go_, (char*)As[pb_] + r_ * 4096 + w * 1024);
      gload16(Bb + go_, (char*)Bs[pb_] + r_ * 4096 + w * 1024);
    }
  };

  const f32x4 z4 = {0.f, 0.f, 0.f, 0.f};
  f32x4 acc[4][4];
#pragma unroll
  for (int i = 0; i < 4; ++i)
#pragma unroll
    for (int j = 0; j < 4; ++j) acc[i][j] = z4;

  gstage(0, 0);
  __syncthreads();
  for (int ks = 0; ks < 8; ++ks) {
    const int pb = ks & 1;
    if (ks < 7) gstage(pb ^ 1, ks + 1);
#pragma unroll
    for (int kk = 0; kk < 2; ++kk) {
      bf16x8 af[4], bfr[4];
#pragma unroll
      for (int i = 0; i < 4; ++i) {
        const int ra = wr * 64 + i * 16 + l15;
        af[i] = *(const bf16x8*)((const char*)As[pb] + ra * 128 + (((kk * 4 + lg) ^ (ra & 7)) * 16));
        const int rb = wc * 64 + i * 16 + l15;
        bfr[i] = *(const bf16x8*)((const char*)Bs[pb] + rb * 128 + (((kk * 4 + lg) ^ (rb & 7)) * 16));
      }
#pragma unroll
      for (int i = 0; i < 4; ++i)
#pragma unroll
        for (int j = 0; j < 4; ++j)
          acc[i][j] = __builtin_amdgcn_mfma_f32_16x16x32_bf16(af[i], bfr[j], acc[i][j], 0, 0, 0);
    }
    __syncthreads();
  }
  OT* Cb = C + (size_t)sCb * b;
#pragma unroll
  for (int i = 0; i < 4; ++i) {
#pragma unroll
    for (int j = 0; j < 4; ++j) {
      const int n = n0 + wc * 64 + j * 16 + l15;
      float bn = 0.f;
      if (BIAS == 2) bn = biasN[n];
#pragma unroll
      for (int r = 0; r < 4; ++r) {
        const int m = m0 + wr * 64 + i * 16 + lg * 4 + r;
        float v = acc[i][j][r] + bn;
        if (BIAS == 1) v += biasM[m];
        if (RESID) v += resid[(size_t)sCb * b + (size_t)m * ldC + n];
        Cb[(size_t)m * ldC + n] = (OT)v;
      }
    }
  }
}

// ---------------- split GEMM (double-buffered): Z = (Ah+Al).(Bh+Bl)^T via 3 products ----------------
__global__ void __launch_bounds__(256) gemm3_k(const bf16_t* __restrict__ Ah,
                                               const bf16_t* __restrict__ Al,
                                               const bf16_t* __restrict__ Bh,
                                               const bf16_t* __restrict__ Bl,
                                               bf16_t* __restrict__ Ch,
                                               bf16_t* __restrict__ Cl,
                                               long sAb, long sCb) {
  __shared__ alignas(16) bf16_t Ash[2][128 * 64];
  __shared__ alignas(16) bf16_t Asl[2][128 * 64];
  __shared__ alignas(16) bf16_t Bsh[2][128 * 64];
  __shared__ alignas(16) bf16_t Bsl[2][128 * 64];
  const int t = threadIdx.x;
  const int lane = t & 63;
  const int w = t >> 6;
  const int wr = w >> 1, wc = w & 1;
  const int l15 = lane & 15, lg = lane >> 4;
  const int b = blockIdx.z;
  const int m0 = blockIdx.y * 128, n0 = blockIdx.x * 128;
  const bf16_t* Ahb = Ah + (size_t)sAb * b + (size_t)m0 * 512;
  const bf16_t* Alb = Al + (size_t)sAb * b + (size_t)m0 * 512;
  const bf16_t* Bhb = Bh + (size_t)n0 * 512;
  const bf16_t* Blb = Bl + (size_t)n0 * 512;
  const int srow = t >> 3;
  const int slot = t & 7;

  auto gstage = [&](int pb_, int ks_) {
#pragma unroll
    for (int r_ = 0; r_ < 4; ++r_) {
      const int rr_ = r_ * 32 + srow;
      const size_t go_ = (size_t)rr_ * 512 + ks_ * 64 + ((slot ^ (rr_ & 7)) * 8);
      gload16(Ahb + go_, (char*)Ash[pb_] + r_ * 4096 + w * 1024);
      gload16(Alb + go_, (char*)Asl[pb_] + r_ * 4096 + w * 1024);
      gload16(Bhb + go_, (char*)Bsh[pb_] + r_ * 4096 + w * 1024);
      gload16(Blb + go_, (char*)Bsl[pb_] + r_ * 4096 + w * 1024);
    }
  };

  const f32x4 z4 = {0.f, 0.f, 0.f, 0.f};
  f32x4 acc[4][4];
#pragma unroll
  for (int i = 0; i < 4; ++i)
#pragma unroll
    for (int j = 0; j < 4; ++j) acc[i][j] = z4;

  gstage(0, 0);
  __syncthreads();
  for (int ks = 0; ks < 8; ++ks) {
    const int pb = ks & 1;
    if (ks < 7) gstage(pb ^ 1, ks + 1);
#pragma unroll
    for (int kk = 0; kk < 2; ++kk) {
      bf16x8 ah[4], al[4], bh[4], bl[4];
#pragma unroll
      for (int i = 0; i < 4; ++i) {
        const int ra = wr * 64 + i * 16 + l15;
        const int sa = (((kk * 4 + lg) ^ (ra & 7)) * 16);
        ah[i] = *(const bf16x8*)((const char*)Ash[pb] + ra * 128 + sa);
        al[i] = *(const bf16x8*)((const char*)Asl[pb] + ra * 128 + sa);
        const int rb = wc * 64 + i * 16 + l15;
        const int sb = (((kk * 4 + lg) ^ (rb & 7)) * 16);
        bh[i] = *(const bf16x8*)((const char*)Bsh[pb] + rb * 128 + sb);
        bl[i] = *(const bf16x8*)((const char*)Bsl[pb] + rb * 128 + sb);
      }
#pragma unroll
      for (int i = 0; i < 4; ++i)
#pragma unroll
        for (int j = 0; j < 4; ++j) {
          acc[i][j] = __builtin_amdgcn_mfma_f32_16x16x32_bf16(ah[i], bh[j], acc[i][j], 0, 0, 0);
          acc[i][j] = __builtin_amdgcn_mfma_f32_16x16x32_bf16(ah[i], bl[j], acc[i][j], 0, 0, 0);
          acc[i][j] = __builtin_amdgcn_mfma_f32_16x16x32_bf16(al[i], bh[j], acc[i][j], 0, 0, 0);
        }
    }
    __syncthreads();
  }
  bf16_t* Chb = Ch + (size_t)sCb * b;
  bf16_t* Clb = Cl + (size_t)sCb * b;
#pragma unroll
  for (int i = 0; i < 4; ++i) {
#pragma unroll
    for (int j = 0; j < 4; ++j) {
      const int n = n0 + wc * 64 + j * 16 + l15;
#pragma unroll
      for (int r = 0; r < 4; ++r) {
        const int m = m0 + wr * 64 + i * 16 + lg * 4 + r;
        const float v = acc[i][j][r];
        const bf16_t hi = (bf16_t)v;
        Chb[(size_t)m * 512 + n] = hi;
        Clb[(size_t)m * 512 + n] = (bf16_t)(v - (float)hi);
      }
    }
  }
}

// ---------------- flash attention v2 ----------------
// Q=(Zh+Zl)[b][q][c] in regs, K=(Xh+Xl)[b][k][c] LDS ping-pong halves, +u[k] from LDS;
// V=Hv[b][c][k] direct global; out Oat[b][c][q]. q=64/block, 8 waves (wq=w&3, wk=w>>2).
__global__ void __launch_bounds__(512, 2) flash_k(const bf16_t* __restrict__ Zh,
                                                  const bf16_t* __restrict__ Zl,
                                                  const bf16_t* __restrict__ Xh,
                                                  const bf16_t* __restrict__ Xl,
                                                  const float* __restrict__ u,
                                                  const bf16_t* __restrict__ Hv,
                                                  bf16_t* __restrict__ Oat) {
  __shared__ alignas(16) bf16_t KH[2][64 * 256];  // 2 x 32KB, 512B rows, slot-swizzled
  __shared__ alignas(16) bf16_t KL[2][64 * 256];  // 2 x 32KB
  __shared__ alignas(16) bf16_t P[64 * 64];       // 8KB, 128B rows, swizzled
  __shared__ float ulds[4096];                    // 16KB
  __shared__ float redm[4][2][16];
  __shared__ float reds[4][2][16];
  __shared__ float alds[64];
  __shared__ float llds[64];

  const int t = threadIdx.x;
  const int lane = t & 63;
  const int w = t >> 6;
  const int wq = w & 3, wk = w >> 2;
  const int l15 = lane & 15, lg = lane >> 4;
  // XCD-aware swizzle: 256 blocks, XCD pair per batch
  const int bid = blockIdx.x;
  const int xcd = bid & 7;
  const int b = xcd >> 1;
  const int q0 = ((xcd & 1) * 32 + (bid >> 3)) * 64;

  const bf16_t* KbH = Xh + (size_t)b * 4096 * 512;
  const bf16_t* KbL = Xl + (size_t)b * 4096 * 512;
  const bf16_t* Vb = Hv + (size_t)b * 512 * 4096;
  const float* ub = u + (size_t)b * 4096;

  const int srow = w * 2 + (lane >> 5);
  const int slot32 = lane & 31;

  auto stagek = [&](int pb_, int kt_, int hf_) {
    const int k0_ = kt_ * 64;
#pragma unroll
    for (int r_ = 0; r_ < 4; ++r_) {
      const int row_ = r_ * 16 + srow;
      const size_t go_ = (size_t)(k0_ + row_) * 512 + hf_ * 256 + ((slot32 ^ (row_ & 7)) * 8);
      gload16(KbH + go_, (char*)KH[pb_] + r_ * 8192 + w * 1024);
      gload16(KbL + go_, (char*)KL[pb_] + r_ * 8192 + w * 1024);
    }
  };

// QK on buffer PB, channel-half HF (literal!): 48 MFMA
#define QKHALF(PB, HF)                                                                         \
  do {                                                                                         \
    _Pragma("unroll") for (int cwl_ = 0; cwl_ < 8; ++cwl_) {                                   \
      const bf16x8 qh_ = qh[(HF) * 8 + cwl_];                                                  \
      const bf16x8 ql_ = ql[(HF) * 8 + cwl_];                                                  \
      _Pragma("unroll") for (int mf_ = 0; mf_ < 2; ++mf_) {                                    \
        const int key_ = 32 * wk + 16 * mf_ + l15;                                             \
        const int so_ = ((cwl_ * 4 + lg) ^ (key_ & 7)) * 16;                                   \
        const bf16x8 kh_ = *(const bf16x8*)((const char*)KH[PB] + key_ * 512 + so_);           \
        const bf16x8 kl_ = *(const bf16x8*)((const char*)KL[PB] + key_ * 512 + so_);           \
        sacc[mf_] = __builtin_amdgcn_mfma_f32_16x16x32_bf16(kh_, qh_, sacc[mf_], 0, 0, 0);     \
        sacc[mf_] = __builtin_amdgcn_mfma_f32_16x16x32_bf16(kh_, ql_, sacc[mf_], 0, 0, 0);     \
        sacc[mf_] = __builtin_amdgcn_mfma_f32_16x16x32_bf16(kl_, qh_, sacc[mf_], 0, 0, 0);     \
      }                                                                                        \
    }                                                                                          \
  } while (0)

  // Q fragments in registers: q = q0 + 16*wq + l15, ch window cw*32 + lg*8
  bf16x8 qh[16], ql[16];
  {
    const size_t qo = ((size_t)b * 4096 + q0 + 16 * wq + l15) * 512 + lg * 8;
#pragma unroll
    for (int cw = 0; cw < 16; ++cw) {
      qh[cw] = *(const bf16x8*)(Zh + qo + cw * 32);
      ql[cw] = *(const bf16x8*)(Zl + qo + cw * 32);
    }
  }
  // stage u[b][*] into LDS (2 rounds), and first K half
#pragma unroll
  for (int r = 0; r < 2; ++r)
    gload16(ub + r * 2048 + w * 256 + lane * 4, (char*)ulds + r * 8192 + w * 1024);
  stagek(0, 0, 0);

  const f32x4 z4 = {0.f, 0.f, 0.f, 0.f};
  f32x4 oacc[4][4];
#pragma unroll
  for (int i = 0; i < 4; ++i)
#pragma unroll
    for (int j = 0; j < 4; ++j) oacc[i][j] = z4;
  float m_run = -3.0e38f, l_run = 0.f;

  __syncthreads();  // ulds + buf0.half0 ready

  for (int kt = 0; kt < 64; ++kt) {
    const int k0 = kt * 64;
    f32x4 sacc[2] = {z4, z4};
    stagek(1, kt, 1);         // issue half1 -> buf1 (flies under QK0)
    QKHALF(0, 0);
    __syncthreads();          // buf1 ready
    if (kt < 63) stagek(0, kt + 1, 0);  // issue next half0 -> buf0 (flies under QK1)
    QKHALF(1, 1);
    // ---- u bias + per-lane max ----
    float pm = -3.0e38f;
#pragma unroll
    for (int mf = 0; mf < 2; ++mf)
#pragma unroll
      for (int j = 0; j < 4; ++j) {
        sacc[mf][j] += ulds[k0 + 32 * wk + 16 * mf + 4 * lg + j];
        pm = fmaxf(pm, sacc[mf][j]);
      }
    pm = fmaxf(pm, __shfl_xor(pm, 16));
    pm = fmaxf(pm, __shfl_xor(pm, 32));
    if (lane < 16) redm[wq][wk][lane] = pm;
    __syncthreads();          // redm ready; buf0(t+1) drained under QK1
    const float m_tile = fmaxf(pm, redm[wq][wk ^ 1][l15]);
    const float m_new = fmaxf(m_run, m_tile);
    const float alpha = exp2f((m_run - m_new) * LOG2E);
    m_run = m_new;
    float ps = 0.f;
    const int qrow = 16 * wq + l15;
    {
      alignas(8) bf16_t pk[4];
#pragma unroll
      for (int mf = 0; mf < 2; ++mf) {
#pragma unroll
        for (int j = 0; j < 4; ++j) {
          const float p = exp2f((sacc[mf][j] - m_new) * LOG2E);
          ps += p;
          pk[j] = (bf16_t)p;
        }
        const int byo = qrow * 128 + ((64 * wk + 32 * mf + 8 * lg) ^ ((qrow & 7) << 4));
        *(uint2*)((char*)P + byo) = *(const uint2*)pk;
      }
    }
    ps += __shfl_xor(ps, 16);
    ps += __shfl_xor(ps, 32);
    if (lane < 16) {
      reds[wq][wk][lane] = ps;
      if (wk == 0) alds[16 * wq + lane] = alpha;
    }
    __syncthreads();          // P / reds / alds ready
    const float s_tile = reds[wq][0][l15] + reds[wq][1][l15];
    l_run = l_run * alpha + s_tile;
    // ---- rescale + PV: oacc[c][q] += V[c][k] * P[q][k] ----
    float aq[4];
#pragma unroll
    for (int qt = 0; qt < 4; ++qt) aq[qt] = alds[16 * qt + l15];
#pragma unroll
    for (int ct = 0; ct < 4; ++ct)
#pragma unroll
      for (int qt = 0; qt < 4; ++qt) oacc[ct][qt] *= aq[qt];
#pragma unroll
    for (int kk = 0; kk < 2; ++kk) {
      bf16x8 bp[4];
#pragma unroll
      for (int qt = 0; qt < 4; ++qt) {
        const int q = 16 * qt + l15;
        bp[qt] = *(const bf16x8*)((const char*)P + q * 128 +
                                  ((kk * 64 + lg * 16) ^ ((q & 7) << 4)));
      }
#pragma unroll
      for (int ct = 0; ct < 4; ++ct) {
        const int c = 64 * w + 16 * ct + l15;
        const bf16x8 vf = *(const bf16x8*)(Vb + (size_t)c * 4096 + k0 + kk * 32 + lg * 8);
#pragma unroll
        for (int qt = 0; qt < 4; ++qt)
          oacc[ct][qt] = __builtin_amdgcn_mfma_f32_16x16x32_bf16(vf, bp[qt], oacc[ct][qt], 0, 0, 0);
      }
    }
  }
#undef QKHALF
  // ---- epilogue: divide by l and store ----
  if (wk == 0 && lane < 16) llds[16 * wq + lane] = l_run;
  __syncthreads();
  float inv[4];
#pragma unroll
  for (int qt = 0; qt < 4; ++qt) inv[qt] = 1.f / llds[16 * qt + l15];
#pragma unroll
  for (int ct = 0; ct < 4; ++ct)
#pragma unroll
    for (int qt = 0; qt < 4; ++qt)
#pragma unroll
      for (int j = 0; j < 4; ++j) {
        const int c = 64 * w + 16 * ct + 4 * lg + j;
        Oat[((size_t)b * 512 + c) * 4096 + q0 + 16 * qt + l15] =
            (bf16_t)(oacc[ct][qt][j] * inv[qt]);
      }
}

// ---------------- host launch ----------------
extern "C" void kernel_launch(void* const* d_in, const int* in_sizes, int n_in,
                              void* d_out, int out_size, void* d_ws, size_t ws_size,
                              hipStream_t stream) {
  const float* x = (const float*)d_in[0];
  const float* fw = (const float*)d_in[1];
  const float* fb = (const float*)d_in[2];
  const float* gw = (const float*)d_in[3];
  const float* gb = (const float*)d_in[4];
  const float* hw = (const float*)d_in[5];
  const float* hb = (const float*)d_in[6];
  const float* ow = (const float*)d_in[7];
  const float* ob = (const float*)d_in[8];
  float* out = (float*)d_out;
  (void)gb;

  const size_t BIG = (size_t)4 * 4096 * 512 * sizeof(bf16_t);  // 16.78MB
  char* p = (char*)d_ws;
  float* mu = (float*)p; p += 2048 * sizeof(float);
  float* rs = (float*)p; p += 2048 * sizeof(float);
  float* vv = (float*)p; p += 512 * sizeof(float);
  float* uu = (float*)p; p += (size_t)4 * 4096 * sizeof(float);
  bf16_t* w2 = (bf16_t*)p; p += (size_t)2 * 512 * 512 * sizeof(bf16_t);
  bf16_t* Mth = (bf16_t*)p; p += (size_t)512 * 512 * sizeof(bf16_t);
  bf16_t* Mtl = (bf16_t*)p; p += (size_t)512 * 512 * sizeof(bf16_t);
  bf16_t* xnh = (bf16_t*)p; p += BIG;
  bf16_t* xnl = (bf16_t*)p; p += BIG;
  bf16_t* xc = (bf16_t*)p; p += BIG;
  bf16_t* Zh = (bf16_t*)p; p += BIG;
  bf16_t* Zl = (bf16_t*)p; p += BIG;
  bf16_t* Hv = (bf16_t*)p; p += BIG;  // total ~103MB
  bf16_t* Oat = xc;     // alias: xc dead after Hv gemm
  bf16_t* Oat_t = xnh;  // alias: xnh dead after flash

  bf16_t* whb = w2;
  bf16_t* wob = w2 + 262144;

  const long sD = (long)4096 * 512;

  stats_k<<<2048, 256, 0, stream>>>(x, mu, rs);
  wcast2_k<<<512, 256, 0, stream>>>(hw, ow, w2);
  mt_k<<<dim3(8, 8), 256, 0, stream>>>(fw, gw, Mth, Mtl);
  v_k<<<2, 256, 0, stream>>>(gw, fb, vv);
  normt_k<<<dim3(64, 8, 4), 256, 0, stream>>>(x, mu, rs, xnh, xnl, xc);
  u_k<<<dim3(1024, 4), 256, 0, stream>>>(vv, xnh, xnl, uu);
  // Z[b][n][j] = sum_i xn[n][i] * Mt[j][i]  (split 3-product)
  gemm3_k<<<dim3(4, 32, 4), 256, 0, stream>>>(xnh, xnl, Mth, Mtl, Zh, Zl, sD, sD);
  // Hv[b][c][n] = h_w . xc  (+h_b over c)
  gemm_k<bf16_t, 1, false><<<dim3(32, 4, 4), 256, 0, stream>>>(
      whb, xc, Hv, hb, nullptr, nullptr, 0, sD, sD, 4096);
  // attention (256 blocks, 512 threads)
  flash_k<<<256, 512, 0, stream>>>(Zh, Zl, xnh, xnl, uu, Hv, Oat);
  // transpose attention output to [b][n][c]
  tbf16_k<<<dim3(64, 8, 4), 256, 0, stream>>>(Oat, Oat_t);
  // out[b][o][n] = o_w . Oat_t^T (+o_b over o) + residual, fp32
  gemm_k<float, 1, true><<<dim3(32, 4, 4), 256, 0, stream>>>(
      wob, Oat_t, out, ob, nullptr, x, 0, sD, sD, 4096);

  (void)in_sizes; (void)n_in; (void)out_size; (void)ws_size;
}

// Round 4
// 425.403 us; speedup vs baseline: 2.6452x; 2.4428x over previous
//
#include <hip/hip_runtime.h>

// Content_SA: instance-norm -> f/g/h 1x1 convs -> attention(QK^T softmax, PV) -> o conv + residual.
// B=4, C=512, H=W=64 (N=4096).
// Precision: energy[n,m] = xn(n)^T M xn(m) + u[m] (+ query-const, cancels in softmax).
// M = f_w^T g_w fp32; Z = xn.M^T computed with split-bf16 3-product (fp32-grade), then Z and xn
// are rounded ONCE to f16 and QK^T is a single f16 MFMA product (logit noise ~16x below bf16 path).
// P/V/O/o-conv all f16. Flash: q=64/block, 8 waves, ch-half ping-pong K staging, V reg-prefetch.

typedef __bf16 bf16_t;
typedef __bf16 bf16x8 __attribute__((ext_vector_type(8)));
typedef _Float16 f16_t;
typedef _Float16 f16x8 __attribute__((ext_vector_type(8)));
typedef float f32x4 __attribute__((ext_vector_type(4)));

#define LOG2E 1.44269504088896340736f

__device__ __forceinline__ void gload16(const void* g, void* l) {
  __builtin_amdgcn_global_load_lds(
      (const __attribute__((address_space(1))) void*)g,
      (__attribute__((address_space(3))) void*)l, 16, 0, 0);
}

// ---------------- instance-norm statistics ----------------
__global__ void __launch_bounds__(256) stats_k(const float* __restrict__ x,
                                               float* __restrict__ mu,
                                               float* __restrict__ rs) {
  const int bc = blockIdx.x;
  const float4* row = (const float4*)(x + (size_t)bc * 4096);
  float s = 0.f, ss = 0.f;
  for (int i = threadIdx.x; i < 1024; i += 256) {
    float4 v = row[i];
    s += v.x + v.y + v.z + v.w;
    ss += v.x * v.x + v.y * v.y + v.z * v.z + v.w * v.w;
  }
#pragma unroll
  for (int o = 32; o >= 1; o >>= 1) {
    s += __shfl_down(s, o);
    ss += __shfl_down(ss, o);
  }
  __shared__ float as_[4], ass_[4];
  const int w = threadIdx.x >> 6;
  if ((threadIdx.x & 63) == 0) { as_[w] = s; ass_[w] = ss; }
  __syncthreads();
  if (threadIdx.x == 0) {
    float st = as_[0] + as_[1] + as_[2] + as_[3];
    float sst = ass_[0] + ass_[1] + ass_[2] + ass_[3];
    float m = st * (1.f / 4096.f);
    float var = sst * (1.f / 4096.f) - m * m;
    mu[bc] = m;
    rs[bc] = rsqrtf(var + 1e-5f);
  }
}

// ---------------- cast h_w, o_w fp32 -> f16 ----------------
__global__ void __launch_bounds__(256) wcast2_k(const float* __restrict__ a,
                                                const float* __restrict__ b,
                                                f16_t* __restrict__ dst) {
  const int i = blockIdx.x * 256 + threadIdx.x;
  const int which = i >> 16;
  const int off = i & 65535;
  const float* s = which ? b : a;
  const float4 v = ((const float4*)s)[off];
  alignas(8) f16_t r[4];
  r[0] = (f16_t)v.x; r[1] = (f16_t)v.y; r[2] = (f16_t)v.z; r[3] = (f16_t)v.w;
  *(uint2*)(dst + ((size_t)which << 18) + (size_t)off * 4) = *(const uint2*)r;
}

// ---------------- Mt[j][i] = sum_c f_w[c][i]*g_w[c][j], fp32, split bf16 hi/lo ----------------
__global__ void __launch_bounds__(256) mt_k(const float* __restrict__ fw,
                                            const float* __restrict__ gw,
                                            bf16_t* __restrict__ Mth,
                                            bf16_t* __restrict__ Mtl) {
  __shared__ float Fs[32][64];
  __shared__ float Gs[32][64];
  const int t = threadIdx.x;
  const int it = blockIdx.x, jt = blockIdx.y;
  float acc[16];
#pragma unroll
  for (int i = 0; i < 16; ++i) acc[i] = 0.f;
  const int jl = t >> 2, ib = (t & 3) * 16;
  const int lr = t >> 4, lc4 = (t & 15) * 4;
  for (int cc = 0; cc < 16; ++cc) {
    __syncthreads();
#pragma unroll
    for (int rep = 0; rep < 2; ++rep) {
      const int r = lr + rep * 16;
      *(float4*)&Fs[r][lc4] = *(const float4*)(fw + (size_t)(cc * 32 + r) * 512 + it * 64 + lc4);
      *(float4*)&Gs[r][lc4] = *(const float4*)(gw + (size_t)(cc * 32 + r) * 512 + jt * 64 + lc4);
    }
    __syncthreads();
#pragma unroll
    for (int c = 0; c < 32; ++c) {
      const float gv = Gs[c][jl];
#pragma unroll
      for (int ii = 0; ii < 16; ++ii) acc[ii] += gv * Fs[c][ib + ii];
    }
  }
  alignas(16) bf16_t hi[16], lo[16];
#pragma unroll
  for (int ii = 0; ii < 16; ++ii) {
    hi[ii] = (bf16_t)acc[ii];
    lo[ii] = (bf16_t)(acc[ii] - (float)hi[ii]);
  }
  const size_t o = (size_t)(jt * 64 + jl) * 512 + it * 64 + ib;
  *(uint4*)(Mth + o) = *(const uint4*)hi;
  *(uint4*)(Mth + o + 8) = *(const uint4*)(hi + 8);
  *(uint4*)(Mtl + o) = *(const uint4*)lo;
  *(uint4*)(Mtl + o + 8) = *(const uint4*)(lo + 8);
}

// ---------------- v[j] = sum_c g_w[c][j] * f_b[c] ----------------
__global__ void __launch_bounds__(256) v_k(const float* __restrict__ gw,
                                           const float* __restrict__ fb,
                                           float* __restrict__ v) {
  const int j = blockIdx.x * 256 + threadIdx.x;
  float s = 0.f;
  for (int c = 0; c < 512; ++c) s += gw[(size_t)c * 512 + j] * fb[c];
  v[j] = s;
}

// ---------------- u[b][m] = v . xn(m) ----------------
__global__ void __launch_bounds__(256) u_k(const float* __restrict__ v,
                                           const bf16_t* __restrict__ xnh,
                                           const bf16_t* __restrict__ xnl,
                                           float* __restrict__ u) {
  const int w = threadIdx.x >> 6, lane = threadIdx.x & 63;
  const int m = blockIdx.x * 4 + w;
  const int b = blockIdx.y;
  const size_t o = ((size_t)b * 4096 + m) * 512 + lane * 8;
  const bf16x8 vh = *(const bf16x8*)(xnh + o);
  const bf16x8 vl = *(const bf16x8*)(xnl + o);
  const float4 v0 = *(const float4*)(v + lane * 8);
  const float4 v1 = *(const float4*)(v + lane * 8 + 4);
  float s = 0.f;
  const float* vp = &v0.x;
#pragma unroll
  for (int e = 0; e < 4; ++e) s += ((float)vh[e] + (float)vl[e]) * vp[e];
  const float* vq = &v1.x;
#pragma unroll
  for (int e = 0; e < 4; ++e) s += ((float)vh[4 + e] + (float)vl[4 + e]) * vq[e];
#pragma unroll
  for (int o2 = 32; o2 >= 1; o2 >>= 1) s += __shfl_down(s, o2);
  if (lane == 0) u[(size_t)b * 4096 + m] = s;
}

// ---------------- normalize + transpose: x[b][c][n] -> xnh/xnl (bf16), xf/xc (f16) [b][n][c] ----------------
__global__ void __launch_bounds__(256) normt_k(const float* __restrict__ x,
                                               const float* __restrict__ mu,
                                               const float* __restrict__ rs,
                                               bf16_t* __restrict__ xnh,
                                               bf16_t* __restrict__ xnl,
                                               f16_t* __restrict__ xf,
                                               f16_t* __restrict__ xc) {
  __shared__ float tile[64][65];
  const int t = threadIdx.x;
  const int nt = blockIdx.x, ct = blockIdx.y, b = blockIdx.z;
  const float* src = x + ((size_t)b * 512 + ct * 64) * 4096 + nt * 64;
  {
    const int r = t >> 4, cq = (t & 15) * 4;
#pragma unroll
    for (int it = 0; it < 4; ++it) {
      const int rr = r + it * 16;
      const float4 v = *(const float4*)(src + (size_t)rr * 4096 + cq);
      tile[rr][cq] = v.x; tile[rr][cq + 1] = v.y;
      tile[rr][cq + 2] = v.z; tile[rr][cq + 3] = v.w;
    }
  }
  __syncthreads();
  const int n = t & 63, ch = t >> 6;
  alignas(16) bf16_t vh[16], vl[16];
  alignas(16) f16_t vf[16], vc[16];
#pragma unroll
  for (int i = 0; i < 16; ++i) {
    const int c = ch * 16 + i;
    const float v = tile[c][n];
    const int gc = b * 512 + ct * 64 + c;
    vc[i] = (f16_t)v;
    const float vn = (v - mu[gc]) * rs[gc];
    const bf16_t h = (bf16_t)vn;
    vh[i] = h;
    vl[i] = (bf16_t)(vn - (float)h);
    vf[i] = (f16_t)vn;
  }
  const size_t o = ((size_t)b * 4096 + nt * 64 + n) * 512 + ct * 64 + ch * 16;
  *(uint4*)(xnh + o) = *(const uint4*)vh;
  *(uint4*)(xnh + o + 8) = *(const uint4*)(vh + 8);
  *(uint4*)(xnl + o) = *(const uint4*)vl;
  *(uint4*)(xnl + o + 8) = *(const uint4*)(vl + 8);
  *(uint4*)(xf + o) = *(const uint4*)vf;
  *(uint4*)(xf + o + 8) = *(const uint4*)(vf + 8);
  *(uint4*)(xc + o) = *(const uint4*)vc;
  *(uint4*)(xc + o + 8) = *(const uint4*)(vc + 8);
}

// ---------------- f16 GEMM (double-buffered, stage-ahead): C[m][n] = A[m][k].Bt[n][k], K=512 ----------------
template <typename OT, int BIAS, bool RESID>
__global__ void __launch_bounds__(256) gemm_k(const f16_t* __restrict__ A,
                                              const f16_t* __restrict__ Bt,
                                              OT* __restrict__ C,
                                              const float* __restrict__ biasM,
                                              const float* __restrict__ biasN,
                                              const float* __restrict__ resid,
                                              long sAb, long sBb, long sCb, int ldC) {
  __shared__ alignas(16) f16_t As[2][128 * 64];
  __shared__ alignas(16) f16_t Bs[2][128 * 64];
  const int t = threadIdx.x;
  const int lane = t & 63;
  const int w = t >> 6;
  const int wr = w >> 1, wc = w & 1;
  const int l15 = lane & 15, lg = lane >> 4;
  const int b = blockIdx.z;
  const int m0 = blockIdx.y * 128, n0 = blockIdx.x * 128;
  const f16_t* Ab = A + (size_t)sAb * b + (size_t)m0 * 512;
  const f16_t* Bb = Bt + (size_t)sBb * b + (size_t)n0 * 512;
  const int srow = t >> 3;
  const int slot = t & 7;

  auto gstage = [&](int pb_, int ks_) {
#pragma unroll
    for (int r_ = 0; r_ < 4; ++r_) {
      const int rr_ = r_ * 32 + srow;
      const size_t go_ = (size_t)rr_ * 512 + ks_ * 64 + ((slot ^ (rr_ & 7)) * 8);
      gload16(Ab + go_, (char*)As[pb_] + r_ * 4096 + w * 1024);
      gload16(Bb + go_, (char*)Bs[pb_] + r_ * 4096 + w * 1024);
    }
  };

  const f32x4 z4 = {0.f, 0.f, 0.f, 0.f};
  f32x4 acc[4][4];
#pragma unroll
  for (int i = 0; i < 4; ++i)
#pragma unroll
    for (int j = 0; j < 4; ++j) acc[i][j] = z4;

  gstage(0, 0);
  __syncthreads();
  for (int ks = 0; ks < 8; ++ks) {
    const int pb = ks & 1;
    if (ks < 7) gstage(pb ^ 1, ks + 1);
#pragma unroll
    for (int kk = 0; kk < 2; ++kk) {
      f16x8 af[4], bfr[4];
#pragma unroll
      for (int i = 0; i < 4; ++i) {
        const int ra = wr * 64 + i * 16 + l15;
        af[i] = *(const f16x8*)((const char*)As[pb] + ra * 128 + (((kk * 4 + lg) ^ (ra & 7)) * 16));
        const int rb = wc * 64 + i * 16 + l15;
        bfr[i] = *(const f16x8*)((const char*)Bs[pb] + rb * 128 + (((kk * 4 + lg) ^ (rb & 7)) * 16));
      }
#pragma unroll
      for (int i = 0; i < 4; ++i)
#pragma unroll
        for (int j = 0; j < 4; ++j)
          acc[i][j] = __builtin_amdgcn_mfma_f32_16x16x32_f16(af[i], bfr[j], acc[i][j], 0, 0, 0);
    }
    __syncthreads();
  }
  OT* Cb = C + (size_t)sCb * b;
#pragma unroll
  for (int i = 0; i < 4; ++i) {
#pragma unroll
    for (int j = 0; j < 4; ++j) {
      const int n = n0 + wc * 64 + j * 16 + l15;
      float bn = 0.f;
      if (BIAS == 2) bn = biasN[n];
#pragma unroll
      for (int r = 0; r < 4; ++r) {
        const int m = m0 + wr * 64 + i * 16 + lg * 4 + r;
        float v = acc[i][j][r] + bn;
        if (BIAS == 1) v += biasM[m];
        if (RESID) v += resid[(size_t)sCb * b + (size_t)m * ldC + n];
        Cb[(size_t)m * ldC + n] = (OT)v;
      }
    }
  }
}

// ---------------- split GEMM: Z = (Ah+Al).(Bh+Bl)^T via 3 bf16 products -> f16 output ----------------
__global__ void __launch_bounds__(256) gemm3_k(const bf16_t* __restrict__ Ah,
                                               const bf16_t* __restrict__ Al,
                                               const bf16_t* __restrict__ Bh,
                                               const bf16_t* __restrict__ Bl,
                                               f16_t* __restrict__ Cf,
                                               long sAb, long sCb) {
  __shared__ alignas(16) bf16_t Ash[2][128 * 64];
  __shared__ alignas(16) bf16_t Asl[2][128 * 64];
  __shared__ alignas(16) bf16_t Bsh[2][128 * 64];
  __shared__ alignas(16) bf16_t Bsl[2][128 * 64];
  const int t = threadIdx.x;
  const int lane = t & 63;
  const int w = t >> 6;
  const int wr = w >> 1, wc = w & 1;
  const int l15 = lane & 15, lg = lane >> 4;
  const int b = blockIdx.z;
  const int m0 = blockIdx.y * 128, n0 = blockIdx.x * 128;
  const bf16_t* Ahb = Ah + (size_t)sAb * b + (size_t)m0 * 512;
  const bf16_t* Alb = Al + (size_t)sAb * b + (size_t)m0 * 512;
  const bf16_t* Bhb = Bh + (size_t)n0 * 512;
  const bf16_t* Blb = Bl + (size_t)n0 * 512;
  const int srow = t >> 3;
  const int slot = t & 7;

  auto gstage = [&](int pb_, int ks_) {
#pragma unroll
    for (int r_ = 0; r_ < 4; ++r_) {
      const int rr_ = r_ * 32 + srow;
      const size_t go_ = (size_t)rr_ * 512 + ks_ * 64 + ((slot ^ (rr_ & 7)) * 8);
      gload16(Ahb + go_, (char*)Ash[pb_] + r_ * 4096 + w * 1024);
      gload16(Alb + go_, (char*)Asl[pb_] + r_ * 4096 + w * 1024);
      gload16(Bhb + go_, (char*)Bsh[pb_] + r_ * 4096 + w * 1024);
      gload16(Blb + go_, (char*)Bsl[pb_] + r_ * 4096 + w * 1024);
    }
  };

  const f32x4 z4 = {0.f, 0.f, 0.f, 0.f};
  f32x4 acc[4][4];
#pragma unroll
  for (int i = 0; i < 4; ++i)
#pragma unroll
    for (int j = 0; j < 4; ++j) acc[i][j] = z4;

  gstage(0, 0);
  __syncthreads();
  for (int ks = 0; ks < 8; ++ks) {
    const int pb = ks & 1;
    if (ks < 7) gstage(pb ^ 1, ks + 1);
#pragma unroll
    for (int kk = 0; kk < 2; ++kk) {
      bf16x8 ah[4], al[4], bh[4], bl[4];
#pragma unroll
      for (int i = 0; i < 4; ++i) {
        const int ra = wr * 64 + i * 16 + l15;
        const int sa = (((kk * 4 + lg) ^ (ra & 7)) * 16);
        ah[i] = *(const bf16x8*)((const char*)Ash[pb] + ra * 128 + sa);
        al[i] = *(const bf16x8*)((const char*)Asl[pb] + ra * 128 + sa);
        const int rb = wc * 64 + i * 16 + l15;
        const int sb = (((kk * 4 + lg) ^ (rb & 7)) * 16);
        bh[i] = *(const bf16x8*)((const char*)Bsh[pb] + rb * 128 + sb);
        bl[i] = *(const bf16x8*)((const char*)Bsl[pb] + rb * 128 + sb);
      }
#pragma unroll
      for (int i = 0; i < 4; ++i)
#pragma unroll
        for (int j = 0; j < 4; ++j) {
          acc[i][j] = __builtin_amdgcn_mfma_f32_16x16x32_bf16(ah[i], bh[j], acc[i][j], 0, 0, 0);
          acc[i][j] = __builtin_amdgcn_mfma_f32_16x16x32_bf16(ah[i], bl[j], acc[i][j], 0, 0, 0);
          acc[i][j] = __builtin_amdgcn_mfma_f32_16x16x32_bf16(al[i], bh[j], acc[i][j], 0, 0, 0);
        }
    }
    __syncthreads();
  }
  f16_t* Cfb = Cf + (size_t)sCb * b;
#pragma unroll
  for (int i = 0; i < 4; ++i) {
#pragma unroll
    for (int j = 0; j < 4; ++j) {
      const int n = n0 + wc * 64 + j * 16 + l15;
#pragma unroll
      for (int r = 0; r < 4; ++r) {
        const int m = m0 + wr * 64 + i * 16 + lg * 4 + r;
        Cfb[(size_t)m * 512 + n] = (f16_t)acc[i][j][r];
      }
    }
  }
}

// ---------------- flash attention v3 (f16, single-product QK) ----------------
// Q=Z[b][q][c] f16 in regs; K=xf[b][k][c] f16, LDS ch-half ping-pong; V=Hv[b][c][k] f16 reg-prefetch;
// out Oat_t[b][q][c] f16 (transposed write -> no tbf16 kernel). 8 waves: wq=w&3 (16q), wk=w>>2 (32k).
__global__ void __launch_bounds__(512, 2) flash_k(const f16_t* __restrict__ Z,
                                                  const f16_t* __restrict__ X,
                                                  const float* __restrict__ u,
                                                  const f16_t* __restrict__ Hv,
                                                  f16_t* __restrict__ Oat_t) {
  __shared__ alignas(16) f16_t K[2][64 * 256];  // 2 x 32KB, 512B rows, slot-swizzled
  __shared__ alignas(16) f16_t P[64 * 64];      // 8KB, 128B rows, swizzled
  __shared__ float ulds[4096];                  // 16KB
  __shared__ float redm[4][2][16];
  __shared__ float reds[4][2][16];
  __shared__ float alds[64];
  __shared__ float llds[64];

  const int t = threadIdx.x;
  const int lane = t & 63;
  const int w = t >> 6;
  const int wq = w & 3, wk = w >> 2;
  const int l15 = lane & 15, lg = lane >> 4;
  const int bid = blockIdx.x;
  const int xcd = bid & 7;
  const int b = xcd >> 1;
  const int q0 = ((xcd & 1) * 32 + (bid >> 3)) * 64;

  const f16_t* Kb = X + (size_t)b * 4096 * 512;
  const f16_t* Vb = Hv + (size_t)b * 512 * 4096;
  const float* ub = u + (size_t)b * 4096;

  const int srow = w * 2 + (lane >> 5);
  const int slot32 = lane & 31;

  auto stagek = [&](int pb_, int kt_, int hf_) {
    const int k0_ = kt_ * 64;
#pragma unroll
    for (int r_ = 0; r_ < 4; ++r_) {
      const int row_ = r_ * 16 + srow;
      const size_t go_ = (size_t)(k0_ + row_) * 512 + hf_ * 256 + ((slot32 ^ (row_ & 7)) * 8);
      gload16(Kb + go_, (char*)K[pb_] + r_ * 8192 + w * 1024);
    }
  };

// QK on buffer PB, channel-half HF: 16 MFMA
#define QKHALF(PB, HF)                                                                        \
  do {                                                                                        \
    _Pragma("unroll") for (int cwl_ = 0; cwl_ < 8; ++cwl_) {                                  \
      const f16x8 qf_ = qf[(HF) * 8 + cwl_];                                                  \
      _Pragma("unroll") for (int mf_ = 0; mf_ < 2; ++mf_) {                                   \
        const int key_ = 32 * wk + 16 * mf_ + l15;                                            \
        const int so_ = ((cwl_ * 4 + lg) ^ (key_ & 7)) * 16;                                  \
        const f16x8 kf_ = *(const f16x8*)((const char*)K[PB] + key_ * 512 + so_);             \
        sacc[mf_] = __builtin_amdgcn_mfma_f32_16x16x32_f16(kf_, qf_, sacc[mf_], 0, 0, 0);     \
      }                                                                                       \
    }                                                                                         \
  } while (0)

  // Q fragments in registers: q = q0 + 16*wq + l15, ch window cw*32 + lg*8
  f16x8 qf[16];
  {
    const size_t qo = ((size_t)b * 4096 + q0 + 16 * wq + l15) * 512 + lg * 8;
#pragma unroll
    for (int cw = 0; cw < 16; ++cw) qf[cw] = *(const f16x8*)(Z + qo + cw * 32);
  }
  // stage u[b][*] into LDS (2 rounds) + first K half
#pragma unroll
  for (int r = 0; r < 2; ++r)
    gload16(ub + r * 2048 + t * 4, (char*)ulds + r * 8192 + w * 1024);
  stagek(0, 0, 0);

  const f32x4 z4 = {0.f, 0.f, 0.f, 0.f};
  f32x4 oacc[4][4];
#pragma unroll
  for (int i = 0; i < 4; ++i)
#pragma unroll
    for (int j = 0; j < 4; ++j) oacc[i][j] = z4;
  float m_run = -3.0e38f, l_run = 0.f;

  __syncthreads();  // ulds + buf0.half0 ready

  for (int kt = 0; kt < 64; ++kt) {
    const int k0 = kt * 64;
    f32x4 sacc[2] = {z4, z4};
    stagek(1, kt, 1);  // half1 -> buf1, flies under QK0
    QKHALF(0, 0);
    __syncthreads();   // buf1 ready
    if (kt < 63) stagek(0, kt + 1, 0);  // next half0 -> buf0, flies under QK1+softmax
    // V prefetch for this tile (flies under QK1+softmax, drained at reds barrier)
    f16x8 vpre[4][2];
#pragma unroll
    for (int ct = 0; ct < 4; ++ct) {
      const int c = 64 * w + 16 * ct + l15;
#pragma unroll
      for (int kk = 0; kk < 2; ++kk)
        vpre[ct][kk] = *(const f16x8*)(Vb + (size_t)c * 4096 + k0 + kk * 32 + lg * 8);
    }
    QKHALF(1, 1);
    // ---- u bias + per-lane max ----
    float pm = -3.0e38f;
#pragma unroll
    for (int mf = 0; mf < 2; ++mf)
#pragma unroll
      for (int j = 0; j < 4; ++j) {
        sacc[mf][j] += ulds[k0 + 32 * wk + 16 * mf + 4 * lg + j];
        pm = fmaxf(pm, sacc[mf][j]);
      }
    pm = fmaxf(pm, __shfl_xor(pm, 16));
    pm = fmaxf(pm, __shfl_xor(pm, 32));
    if (lane < 16) redm[wq][wk][lane] = pm;
    __syncthreads();
    const float m_tile = fmaxf(pm, redm[wq][wk ^ 1][l15]);
    const float m_new = fmaxf(m_run, m_tile);
    const float alpha = exp2f((m_run - m_new) * LOG2E);
    m_run = m_new;
    float ps = 0.f;
    const int qrow = 16 * wq + l15;
    {
      alignas(8) f16_t pk[4];
#pragma unroll
      for (int mf = 0; mf < 2; ++mf) {
#pragma unroll
        for (int j = 0; j < 4; ++j) {
          const float p = exp2f((sacc[mf][j] - m_new) * LOG2E);
          ps += p;
          pk[j] = (f16_t)p;
        }
        const int byo = qrow * 128 + ((64 * wk + 32 * mf + 8 * lg) ^ ((qrow & 7) << 4));
        *(uint2*)((char*)P + byo) = *(const uint2*)pk;
      }
    }
    ps += __shfl_xor(ps, 16);
    ps += __shfl_xor(ps, 32);
    if (lane < 16) {
      reds[wq][wk][lane] = ps;
      if (wk == 0) alds[16 * wq + lane] = alpha;
    }
    __syncthreads();  // P / reds / alds ready (drains buf0 + V prefetch)
    const float s_tile = reds[wq][0][l15] + reds[wq][1][l15];
    l_run = l_run * alpha + s_tile;
    // ---- rescale + PV: oacc[c][q] += V[c][k] * P[q][k] ----
    float aq[4];
#pragma unroll
    for (int qt = 0; qt < 4; ++qt) aq[qt] = alds[16 * qt + l15];
#pragma unroll
    for (int ct = 0; ct < 4; ++ct)
#pragma unroll
      for (int qt = 0; qt < 4; ++qt) oacc[ct][qt] *= aq[qt];
#pragma unroll
    for (int kk = 0; kk < 2; ++kk) {
      f16x8 bp[4];
#pragma unroll
      for (int qt = 0; qt < 4; ++qt) {
        const int q = 16 * qt + l15;
        bp[qt] = *(const f16x8*)((const char*)P + q * 128 +
                                 ((kk * 64 + lg * 16) ^ ((q & 7) << 4)));
      }
#pragma unroll
      for (int ct = 0; ct < 4; ++ct)
#pragma unroll
        for (int qt = 0; qt < 4; ++qt)
          oacc[ct][qt] =
              __builtin_amdgcn_mfma_f32_16x16x32_f16(vpre[ct][kk], bp[qt], oacc[ct][qt], 0, 0, 0);
    }
  }
#undef QKHALF
  // ---- epilogue: divide by l, store transposed [q][c] ----
  if (wk == 0 && lane < 16) llds[16 * wq + lane] = l_run;
  __syncthreads();
  float inv[4];
#pragma unroll
  for (int qt = 0; qt < 4; ++qt) inv[qt] = 1.f / llds[16 * qt + l15];
#pragma unroll
  for (int ct = 0; ct < 4; ++ct)
#pragma unroll
    for (int qt = 0; qt < 4; ++qt) {
      alignas(8) f16_t o4[4];
#pragma unroll
      for (int j = 0; j < 4; ++j) o4[j] = (f16_t)(oacc[ct][qt][j] * inv[qt]);
      *(uint2*)(Oat_t + ((size_t)b * 4096 + q0 + 16 * qt + l15) * 512 + 64 * w + 16 * ct + 4 * lg) =
          *(const uint2*)o4;
    }
}

// ---------------- host launch ----------------
extern "C" void kernel_launch(void* const* d_in, const int* in_sizes, int n_in,
                              void* d_out, int out_size, void* d_ws, size_t ws_size,
                              hipStream_t stream) {
  const float* x = (const float*)d_in[0];
  const float* fw = (const float*)d_in[1];
  const float* fb = (const float*)d_in[2];
  const float* gw = (const float*)d_in[3];
  const float* gb = (const float*)d_in[4];
  const float* hw = (const float*)d_in[5];
  const float* hb = (const float*)d_in[6];
  const float* ow = (const float*)d_in[7];
  const float* ob = (const float*)d_in[8];
  float* out = (float*)d_out;
  (void)gb;

  const size_t BIG = (size_t)4 * 4096 * 512 * sizeof(bf16_t);  // 16.78MB
  char* p = (char*)d_ws;
  float* mu = (float*)p; p += 2048 * sizeof(float);
  float* rs = (float*)p; p += 2048 * sizeof(float);
  float* vv = (float*)p; p += 512 * sizeof(float);
  float* uu = (float*)p; p += (size_t)4 * 4096 * sizeof(float);
  f16_t* w2 = (f16_t*)p; p += (size_t)2 * 512 * 512 * sizeof(f16_t);
  bf16_t* Mth = (bf16_t*)p; p += (size_t)512 * 512 * sizeof(bf16_t);
  bf16_t* Mtl = (bf16_t*)p; p += (size_t)512 * 512 * sizeof(bf16_t);
  bf16_t* xnh = (bf16_t*)p; p += BIG;
  bf16_t* xnl = (bf16_t*)p; p += BIG;
  f16_t* xf = (f16_t*)p; p += BIG;
  f16_t* xc = (f16_t*)p; p += BIG;
  f16_t* Zf = (f16_t*)p; p += BIG;
  f16_t* Hv = (f16_t*)p; p += BIG;  // total ~103MB
  f16_t* Oat_t = xc;                // alias: xc dead after Hv gemm

  f16_t* whb = w2;
  f16_t* wob = w2 + 262144;

  const long sD = (long)4096 * 512;

  stats_k<<<2048, 256, 0, stream>>>(x, mu, rs);
  wcast2_k<<<512, 256, 0, stream>>>(hw, ow, w2);
  mt_k<<<dim3(8, 8), 256, 0, stream>>>(fw, gw, Mth, Mtl);
  v_k<<<2, 256, 0, stream>>>(gw, fb, vv);
  normt_k<<<dim3(64, 8, 4), 256, 0, stream>>>(x, mu, rs, xnh, xnl, xf, xc);
  u_k<<<dim3(1024, 4), 256, 0, stream>>>(vv, xnh, xnl, uu);
  // Z[b][n][j] = sum_i xn[n][i] * Mt[j][i]  (split 3-product, f16 out)
  gemm3_k<<<dim3(4, 32, 4), 256, 0, stream>>>(xnh, xnl, Mth, Mtl, Zf, sD, sD);
  // Hv[b][c][n] = h_w . xc  (+h_b over c)
  gemm_k<f16_t, 1, false><<<dim3(32, 4, 4), 256, 0, stream>>>(
      whb, xc, Hv, hb, nullptr, nullptr, 0, sD, sD, 4096);
  // attention (256 blocks, 512 threads) -> Oat_t[b][q][c]
  flash_k<<<256, 512, 0, stream>>>(Zf, xf, uu, Hv, Oat_t);
  // out[b][o][n] = o_w . Oat_t^T (+o_b over o) + residual, fp32
  gemm_k<float, 1, true><<<dim3(32, 4, 4), 256, 0, stream>>>(
      wob, Oat_t, out, ob, nullptr, x, 0, sD, sD, 4096);

  (void)in_sizes; (void)n_in; (void)out_size; (void)ws_size;
}

// Round 5
// 404.148 us; speedup vs baseline: 2.7843x; 1.0526x over previous
//
#include <hip/hip_runtime.h>

// Content_SA: instance-norm -> f/g/h 1x1 convs -> attention(QK^T softmax, PV) -> o conv + residual.
// B=4, C=512, H=W=64 (N=4096).
// Algebra: energy[n,m] = xn(n)^T M xn(m) + u[m] (+ query-const, cancels in softmax), M = f_w^T g_w (fp32).
// Precision: M,Z,xn,V all f16 (single rounding from fp32-grade values); softmax fp32.
// Flash v4: q=64/block, 8 waves, raw s_barrier + counted vmcnt (T3/T4), setprio (T5), defer-max (T13).

typedef __bf16 bf16_t;
typedef _Float16 f16_t;
typedef _Float16 f16x8 __attribute__((ext_vector_type(8)));
typedef float f32x4 __attribute__((ext_vector_type(4)));

#define LOG2E 1.44269504088896340736f

__device__ __forceinline__ void gload16(const void* g, void* l) {
  __builtin_amdgcn_global_load_lds(
      (const __attribute__((address_space(1))) void*)g,
      (__attribute__((address_space(3))) void*)l, 16, 0, 0);
}

#define WAITV14() asm volatile("s_waitcnt vmcnt(14)" ::: "memory")
#define WAITV10() asm volatile("s_waitcnt vmcnt(10)" ::: "memory")
#define WAITL() asm volatile("s_waitcnt lgkmcnt(0)" ::: "memory")
#define SB() __builtin_amdgcn_s_barrier()
#define SCHED0() __builtin_amdgcn_sched_barrier(0)

// ---------------- instance-norm statistics ----------------
__global__ void __launch_bounds__(256) stats_k(const float* __restrict__ x,
                                               float* __restrict__ mu,
                                               float* __restrict__ rs) {
  const int bc = blockIdx.x;
  const float4* row = (const float4*)(x + (size_t)bc * 4096);
  float s = 0.f, ss = 0.f;
  for (int i = threadIdx.x; i < 1024; i += 256) {
    float4 v = row[i];
    s += v.x + v.y + v.z + v.w;
    ss += v.x * v.x + v.y * v.y + v.z * v.z + v.w * v.w;
  }
#pragma unroll
  for (int o = 32; o >= 1; o >>= 1) {
    s += __shfl_down(s, o);
    ss += __shfl_down(ss, o);
  }
  __shared__ float as_[4], ass_[4];
  const int w = threadIdx.x >> 6;
  if ((threadIdx.x & 63) == 0) { as_[w] = s; ass_[w] = ss; }
  __syncthreads();
  if (threadIdx.x == 0) {
    float st = as_[0] + as_[1] + as_[2] + as_[3];
    float sst = ass_[0] + ass_[1] + ass_[2] + ass_[3];
    float m = st * (1.f / 4096.f);
    float var = sst * (1.f / 4096.f) - m * m;
    mu[bc] = m;
    rs[bc] = rsqrtf(var + 1e-5f);
  }
}

// ---------------- cast h_w, o_w fp32 -> f16 ----------------
__global__ void __launch_bounds__(256) wcast2_k(const float* __restrict__ a,
                                                const float* __restrict__ b,
                                                f16_t* __restrict__ dst) {
  const int i = blockIdx.x * 256 + threadIdx.x;
  const int which = i >> 16;
  const int off = i & 65535;
  const float* s = which ? b : a;
  const float4 v = ((const float4*)s)[off];
  alignas(8) f16_t r[4];
  r[0] = (f16_t)v.x; r[1] = (f16_t)v.y; r[2] = (f16_t)v.z; r[3] = (f16_t)v.w;
  *(uint2*)(dst + ((size_t)which << 18) + (size_t)off * 4) = *(const uint2*)r;
}

// ---------------- Mt[j][i] = sum_c f_w[c][i]*g_w[c][j], fp32 acc -> f16 ----------------
__global__ void __launch_bounds__(256) mt_k(const float* __restrict__ fw,
                                            const float* __restrict__ gw,
                                            f16_t* __restrict__ Mh) {
  __shared__ float Fs[32][64];
  __shared__ float Gs[32][64];
  const int t = threadIdx.x;
  const int it = blockIdx.x, jt = blockIdx.y;
  float acc[16];
#pragma unroll
  for (int i = 0; i < 16; ++i) acc[i] = 0.f;
  const int jl = t >> 2, ib = (t & 3) * 16;
  const int lr = t >> 4, lc4 = (t & 15) * 4;
  for (int cc = 0; cc < 16; ++cc) {
    __syncthreads();
#pragma unroll
    for (int rep = 0; rep < 2; ++rep) {
      const int r = lr + rep * 16;
      *(float4*)&Fs[r][lc4] = *(const float4*)(fw + (size_t)(cc * 32 + r) * 512 + it * 64 + lc4);
      *(float4*)&Gs[r][lc4] = *(const float4*)(gw + (size_t)(cc * 32 + r) * 512 + jt * 64 + lc4);
    }
    __syncthreads();
#pragma unroll
    for (int c = 0; c < 32; ++c) {
      const float gv = Gs[c][jl];
#pragma unroll
      for (int ii = 0; ii < 16; ++ii) acc[ii] += gv * Fs[c][ib + ii];
    }
  }
  alignas(16) f16_t hi[16];
#pragma unroll
  for (int ii = 0; ii < 16; ++ii) hi[ii] = (f16_t)acc[ii];
  const size_t o = (size_t)(jt * 64 + jl) * 512 + it * 64 + ib;
  *(uint4*)(Mh + o) = *(const uint4*)hi;
  *(uint4*)(Mh + o + 8) = *(const uint4*)(hi + 8);
}

// ---------------- v[j] = sum_c g_w[c][j] * f_b[c] ----------------
__global__ void __launch_bounds__(256) v_k(const float* __restrict__ gw,
                                           const float* __restrict__ fb,
                                           float* __restrict__ v) {
  const int j = blockIdx.x * 256 + threadIdx.x;
  float s = 0.f;
  for (int c = 0; c < 512; ++c) s += gw[(size_t)c * 512 + j] * fb[c];
  v[j] = s;
}

// ---------------- u[b][m] = v . xn(m) ----------------
__global__ void __launch_bounds__(256) u_k(const float* __restrict__ v,
                                           const f16_t* __restrict__ xf,
                                           float* __restrict__ u) {
  const int w = threadIdx.x >> 6, lane = threadIdx.x & 63;
  const int m = blockIdx.x * 4 + w;
  const int b = blockIdx.y;
  const size_t o = ((size_t)b * 4096 + m) * 512 + lane * 8;
  const f16x8 vh = *(const f16x8*)(xf + o);
  const float4 v0 = *(const float4*)(v + lane * 8);
  const float4 v1 = *(const float4*)(v + lane * 8 + 4);
  float s = 0.f;
  const float* vp = &v0.x;
#pragma unroll
  for (int e = 0; e < 4; ++e) s += (float)vh[e] * vp[e];
  const float* vq = &v1.x;
#pragma unroll
  for (int e = 0; e < 4; ++e) s += (float)vh[4 + e] * vq[e];
#pragma unroll
  for (int o2 = 32; o2 >= 1; o2 >>= 1) s += __shfl_down(s, o2);
  if (lane == 0) u[(size_t)b * 4096 + m] = s;
}

// ---------------- normalize + transpose: x[b][c][n] -> xf (norm f16), xc (raw f16) [b][n][c] ----------------
__global__ void __launch_bounds__(256) normt_k(const float* __restrict__ x,
                                               const float* __restrict__ mu,
                                               const float* __restrict__ rs,
                                               f16_t* __restrict__ xf,
                                               f16_t* __restrict__ xc) {
  __shared__ float tile[64][65];
  const int t = threadIdx.x;
  const int nt = blockIdx.x, ct = blockIdx.y, b = blockIdx.z;
  const float* src = x + ((size_t)b * 512 + ct * 64) * 4096 + nt * 64;
  {
    const int r = t >> 4, cq = (t & 15) * 4;
#pragma unroll
    for (int it = 0; it < 4; ++it) {
      const int rr = r + it * 16;
      const float4 v = *(const float4*)(src + (size_t)rr * 4096 + cq);
      tile[rr][cq] = v.x; tile[rr][cq + 1] = v.y;
      tile[rr][cq + 2] = v.z; tile[rr][cq + 3] = v.w;
    }
  }
  __syncthreads();
  const int n = t & 63, ch = t >> 6;
  alignas(16) f16_t vf[16], vc[16];
#pragma unroll
  for (int i = 0; i < 16; ++i) {
    const int c = ch * 16 + i;
    const float v = tile[c][n];
    const int gc = b * 512 + ct * 64 + c;
    vc[i] = (f16_t)v;
    vf[i] = (f16_t)((v - mu[gc]) * rs[gc]);
  }
  const size_t o = ((size_t)b * 4096 + nt * 64 + n) * 512 + ct * 64 + ch * 16;
  *(uint4*)(xf + o) = *(const uint4*)vf;
  *(uint4*)(xf + o + 8) = *(const uint4*)(vf + 8);
  *(uint4*)(xc + o) = *(const uint4*)vc;
  *(uint4*)(xc + o + 8) = *(const uint4*)(vc + 8);
}

// ---------------- f16 GEMM (double-buffered, stage-ahead): C[m][n] = A[m][k].Bt[n][k], K=512 ----------------
template <typename OT, int BIAS, bool RESID>
__global__ void __launch_bounds__(256) gemm_k(const f16_t* __restrict__ A,
                                              const f16_t* __restrict__ Bt,
                                              OT* __restrict__ C,
                                              const float* __restrict__ biasM,
                                              const float* __restrict__ biasN,
                                              const float* __restrict__ resid,
                                              long sAb, long sBb, long sCb, int ldC) {
  __shared__ alignas(16) f16_t As[2][128 * 64];
  __shared__ alignas(16) f16_t Bs[2][128 * 64];
  const int t = threadIdx.x;
  const int lane = t & 63;
  const int w = t >> 6;
  const int wr = w >> 1, wc = w & 1;
  const int l15 = lane & 15, lg = lane >> 4;
  const int b = blockIdx.z;
  const int m0 = blockIdx.y * 128, n0 = blockIdx.x * 128;
  const f16_t* Ab = A + (size_t)sAb * b + (size_t)m0 * 512;
  const f16_t* Bb = Bt + (size_t)sBb * b + (size_t)n0 * 512;
  const int srow = t >> 3;
  const int slot = t & 7;

  auto gstage = [&](int pb_, int ks_) {
#pragma unroll
    for (int r_ = 0; r_ < 4; ++r_) {
      const int rr_ = r_ * 32 + srow;
      const size_t go_ = (size_t)rr_ * 512 + ks_ * 64 + ((slot ^ (rr_ & 7)) * 8);
      gload16(Ab + go_, (char*)As[pb_] + r_ * 4096 + w * 1024);
      gload16(Bb + go_, (char*)Bs[pb_] + r_ * 4096 + w * 1024);
    }
  };

  const f32x4 z4 = {0.f, 0.f, 0.f, 0.f};
  f32x4 acc[4][4];
#pragma unroll
  for (int i = 0; i < 4; ++i)
#pragma unroll
    for (int j = 0; j < 4; ++j) acc[i][j] = z4;

  gstage(0, 0);
  __syncthreads();
  for (int ks = 0; ks < 8; ++ks) {
    const int pb = ks & 1;
    if (ks < 7) gstage(pb ^ 1, ks + 1);
#pragma unroll
    for (int kk = 0; kk < 2; ++kk) {
      f16x8 af[4], bfr[4];
#pragma unroll
      for (int i = 0; i < 4; ++i) {
        const int ra = wr * 64 + i * 16 + l15;
        af[i] = *(const f16x8*)((const char*)As[pb] + ra * 128 + (((kk * 4 + lg) ^ (ra & 7)) * 16));
        const int rb = wc * 64 + i * 16 + l15;
        bfr[i] = *(const f16x8*)((const char*)Bs[pb] + rb * 128 + (((kk * 4 + lg) ^ (rb & 7)) * 16));
      }
#pragma unroll
      for (int i = 0; i < 4; ++i)
#pragma unroll
        for (int j = 0; j < 4; ++j)
          acc[i][j] = __builtin_amdgcn_mfma_f32_16x16x32_f16(af[i], bfr[j], acc[i][j], 0, 0, 0);
    }
    __syncthreads();
  }
  OT* Cb = C + (size_t)sCb * b;
#pragma unroll
  for (int i = 0; i < 4; ++i) {
#pragma unroll
    for (int j = 0; j < 4; ++j) {
      const int n = n0 + wc * 64 + j * 16 + l15;
      float bn = 0.f;
      if (BIAS == 2) bn = biasN[n];
#pragma unroll
      for (int r = 0; r < 4; ++r) {
        const int m = m0 + wr * 64 + i * 16 + lg * 4 + r;
        float v = acc[i][j][r] + bn;
        if (BIAS == 1) v += biasM[m];
        if (RESID) v += resid[(size_t)sCb * b + (size_t)m * ldC + n];
        Cb[(size_t)m * ldC + n] = (OT)v;
      }
    }
  }
}

// ---------------- flash attention v4: counted-vmcnt raw-barrier schedule ----------------
// Q=Z[b][q][c] f16 in regs; K=xf[b][k][c] f16 LDS ch-half ping-pong; V=Hv[b][c][k] reg-prefetch;
// u per-tile reg loads; out Oat_t[b][q][c]. 8 waves: wq=w&3 (16q), wk=w>>2 (32k).
// VMEM issue ledger per tile (steady state): [K0stage(4), K1stage(4)] outstanding at top;
// issue u(2)+vpre(8) -> WAITV14 retires K0stage; after QK0 WAITV10 retires K1stage;
// compiler retires u at softmax (vmcnt 12) and vpre at PV (vmcnt 8), keeping next stages flying.
__global__ void __launch_bounds__(512, 2) flash_k(const f16_t* __restrict__ Z,
                                                  const f16_t* __restrict__ X,
                                                  const float* __restrict__ u,
                                                  const f16_t* __restrict__ Hv,
                                                  f16_t* __restrict__ Oat_t) {
  __shared__ alignas(16) f16_t K[2][64 * 256];  // 2 x 32KB, 512B rows, slot-swizzled
  __shared__ alignas(16) f16_t P[64 * 72];      // 9KB, 144B rows (bank-balanced, no swizzle)
  __shared__ float redm[4][2][16];
  __shared__ float reds[4][2][16];
  __shared__ float alds[64];
  __shared__ float llds[64];

  const int t = threadIdx.x;
  const int lane = t & 63;
  const int w = t >> 6;
  const int wq = w & 3, wk = w >> 2;
  const int l15 = lane & 15, lg = lane >> 4;
  const int bid = blockIdx.x;
  const int xcd = bid & 7;
  const int b = xcd >> 1;
  const int q0 = ((xcd & 1) * 32 + (bid >> 3)) * 64;

  const f16_t* Kb = X + (size_t)b * 4096 * 512;
  const f16_t* Vb = Hv + (size_t)b * 512 * 4096;
  const float* ub = u + (size_t)b * 4096;

  const int srow = w * 2 + (lane >> 5);
  const int slot32 = lane & 31;

  auto stagek = [&](int pb_, int kt_, int hf_) {
    const int k0_ = kt_ * 64;
#pragma unroll
    for (int r_ = 0; r_ < 4; ++r_) {
      const int row_ = r_ * 16 + srow;
      const size_t go_ = (size_t)(k0_ + row_) * 512 + hf_ * 256 + ((slot32 ^ (row_ & 7)) * 8);
      gload16(Kb + go_, (char*)K[pb_] + r_ * 8192 + w * 1024);
    }
  };

// QK on buffer PB, channel-half HF: 16 MFMA
#define QKHALF(PB, HF)                                                                        \
  do {                                                                                        \
    _Pragma("unroll") for (int cwl_ = 0; cwl_ < 8; ++cwl_) {                                  \
      const f16x8 qf_ = qf[(HF) * 8 + cwl_];                                                  \
      _Pragma("unroll") for (int mf_ = 0; mf_ < 2; ++mf_) {                                   \
        const int key_ = 32 * wk + 16 * mf_ + l15;                                            \
        const int so_ = ((cwl_ * 4 + lg) ^ (key_ & 7)) * 16;                                  \
        const f16x8 kf_ = *(const f16x8*)((const char*)K[PB] + key_ * 512 + so_);             \
        sacc[mf_] = __builtin_amdgcn_mfma_f32_16x16x32_f16(kf_, qf_, sacc[mf_], 0, 0, 0);     \
      }                                                                                       \
    }                                                                                         \
  } while (0)

  // Q fragments in registers: q = q0 + 16*wq + l15, ch window cw*32 + lg*8
  f16x8 qf[16];
  {
    const size_t qo = ((size_t)b * 4096 + q0 + 16 * wq + l15) * 512 + lg * 8;
#pragma unroll
    for (int cw = 0; cw < 16; ++cw) qf[cw] = *(const f16x8*)(Z + qo + cw * 32);
  }
  // prologue staging: tile 0 both halves (issue order K0 then K1 matches steady-state ledger)
  stagek(0, 0, 0);
  stagek(1, 0, 1);

  const f32x4 z4 = {0.f, 0.f, 0.f, 0.f};
  f32x4 oacc[4][4];
#pragma unroll
  for (int i = 0; i < 4; ++i)
#pragma unroll
    for (int j = 0; j < 4; ++j) oacc[i][j] = z4;
  float m_run = -3.0e38f, l_run = 0.f;

  for (int kt = 0; kt < 64; ++kt) {
    const int k0 = kt * 64;
    const int ktn = (kt + 1) & 63;  // wrap: uniform issue counts, no branches
    f32x4 sacc[2] = {z4, z4};
    // ---- issue this tile's u + V register loads (10 VMEM) ----
    const float4 u0 = *(const float4*)(ub + k0 + 32 * wk + 4 * lg);
    const float4 u1 = *(const float4*)(ub + k0 + 32 * wk + 16 + 4 * lg);
    f16x8 vpre[4][2];
#pragma unroll
    for (int ct = 0; ct < 4; ++ct) {
      const int c = 64 * w + 16 * ct + l15;
#pragma unroll
      for (int kk = 0; kk < 2; ++kk)
        vpre[ct][kk] = *(const f16x8*)(Vb + (size_t)c * 4096 + k0 + kk * 32 + lg * 8);
    }
    // ---- K[0] (t.h0) ready: retire its 4 stage loads, keep K1(4)+u(2)+vpre(8)=14 ----
    WAITV14(); WAITL(); SB(); SCHED0();
    __builtin_amdgcn_s_setprio(1);
    QKHALF(0, 0);
    __builtin_amdgcn_s_setprio(0);
    // ---- K[1] (t.h1) ready: retire its 4, keep u+vpre=10; own QK0 ds reads done (lgkm) ----
    WAITL(); WAITV10(); SB(); SCHED0();
    stagek(0, ktn, 0);  // restage K[0] <- next h0 (safe: all waves past barrier)
    __builtin_amdgcn_s_setprio(1);
    QKHALF(1, 1);
    __builtin_amdgcn_s_setprio(0);
    // ---- u bias + per-lane max (compiler retires u here, vmcnt keeps vpre+K0stage) ----
    float pm = -3.0e38f;
    {
      const float* up0 = &u0.x;
      const float* up1 = &u1.x;
#pragma unroll
      for (int j = 0; j < 4; ++j) {
        sacc[0][j] += up0[j];
        sacc[1][j] += up1[j];
        pm = fmaxf(pm, fmaxf(sacc[0][j], sacc[1][j]));
      }
    }
    pm = fmaxf(pm, __shfl_xor(pm, 16));
    pm = fmaxf(pm, __shfl_xor(pm, 32));
    if (lane < 16) redm[wq][wk][lane] = pm;
    WAITL(); SB(); SCHED0();   // redm visible; everyone's QK1 reads done
    stagek(1, ktn, 1);         // restage K[1] <- next h1
    // ---- softmax finish with defer-max (THR=8) ----
    const float m_tile = fmaxf(pm, redm[wq][wk ^ 1][l15]);
    float alpha;
    if (m_tile > m_run + 8.f) {
      alpha = exp2f((m_run - m_tile) * LOG2E);
      m_run = m_tile;
    } else {
      alpha = 1.f;
    }
    float ps = 0.f;
    const int qrow = 16 * wq + l15;
    {
      alignas(8) f16_t pk[4];
#pragma unroll
      for (int mf = 0; mf < 2; ++mf) {
#pragma unroll
        for (int j = 0; j < 4; ++j) {
          const float p = exp2f((sacc[mf][j] - m_run) * LOG2E);
          ps += p;
          pk[j] = (f16_t)p;
        }
        *(uint2*)((char*)P + qrow * 144 + 64 * wk + 32 * mf + 8 * lg) = *(const uint2*)pk;
      }
    }
    ps += __shfl_xor(ps, 16);
    ps += __shfl_xor(ps, 32);
    if (lane < 16) {
      reds[wq][wk][lane] = ps;
      if (wk == 0) alds[16 * wq + lane] = alpha;
    }
    WAITL(); SB(); SCHED0();   // P / reds / alds visible
    const float s_tile = reds[wq][0][l15] + reds[wq][1][l15];
    l_run = l_run * alpha + s_tile;
    // ---- rescale (skippable) + PV: oacc[c][q] += V[c][k] * P[q][k] ----
    float aq[4];
#pragma unroll
    for (int qt = 0; qt < 4; ++qt) aq[qt] = alds[16 * qt + l15];
    const bool need = (aq[0] != 1.f) || (aq[1] != 1.f) || (aq[2] != 1.f) || (aq[3] != 1.f);
    if (__any(need)) {
#pragma unroll
      for (int ct = 0; ct < 4; ++ct)
#pragma unroll
        for (int qt = 0; qt < 4; ++qt) oacc[ct][qt] *= aq[qt];
    }
    __builtin_amdgcn_s_setprio(1);
#pragma unroll
    for (int kk = 0; kk < 2; ++kk) {
      f16x8 bp[4];
#pragma unroll
      for (int qt = 0; qt < 4; ++qt) {
        const int q = 16 * qt + l15;
        bp[qt] = *(const f16x8*)((const char*)P + q * 144 + kk * 64 + lg * 16);
      }
#pragma unroll
      for (int ct = 0; ct < 4; ++ct)
#pragma unroll
        for (int qt = 0; qt < 4; ++qt)
          oacc[ct][qt] =
              __builtin_amdgcn_mfma_f32_16x16x32_f16(vpre[ct][kk], bp[qt], oacc[ct][qt], 0, 0, 0);
    }
    __builtin_amdgcn_s_setprio(0);
  }
#undef QKHALF
  // ---- epilogue: divide by l, store transposed [q][c] ----
  if (wk == 0 && lane < 16) llds[16 * wq + lane] = l_run;
  __syncthreads();
  float inv[4];
#pragma unroll
  for (int qt = 0; qt < 4; ++qt) inv[qt] = 1.f / llds[16 * qt + l15];
#pragma unroll
  for (int ct = 0; ct < 4; ++ct)
#pragma unroll
    for (int qt = 0; qt < 4; ++qt) {
      alignas(8) f16_t o4[4];
#pragma unroll
      for (int j = 0; j < 4; ++j) o4[j] = (f16_t)(oacc[ct][qt][j] * inv[qt]);
      *(uint2*)(Oat_t + ((size_t)b * 4096 + q0 + 16 * qt + l15) * 512 + 64 * w + 16 * ct + 4 * lg) =
          *(const uint2*)o4;
    }
}

// ---------------- host launch ----------------
extern "C" void kernel_launch(void* const* d_in, const int* in_sizes, int n_in,
                              void* d_out, int out_size, void* d_ws, size_t ws_size,
                              hipStream_t stream) {
  const float* x = (const float*)d_in[0];
  const float* fw = (const float*)d_in[1];
  const float* fb = (const float*)d_in[2];
  const float* gw = (const float*)d_in[3];
  const float* gb = (const float*)d_in[4];
  const float* hw = (const float*)d_in[5];
  const float* hb = (const float*)d_in[6];
  const float* ow = (const float*)d_in[7];
  const float* ob = (const float*)d_in[8];
  float* out = (float*)d_out;
  (void)gb;

  const size_t BIG = (size_t)4 * 4096 * 512 * sizeof(f16_t);  // 16.78MB
  char* p = (char*)d_ws;
  float* mu = (float*)p; p += 2048 * sizeof(float);
  float* rs = (float*)p; p += 2048 * sizeof(float);
  float* vv = (float*)p; p += 512 * sizeof(float);
  float* uu = (float*)p; p += (size_t)4 * 4096 * sizeof(float);
  f16_t* w2 = (f16_t*)p; p += (size_t)2 * 512 * 512 * sizeof(f16_t);
  f16_t* Mh = (f16_t*)p; p += (size_t)512 * 512 * sizeof(f16_t);
  f16_t* xf = (f16_t*)p; p += BIG;
  f16_t* xc = (f16_t*)p; p += BIG;
  f16_t* Zf = (f16_t*)p; p += BIG;
  f16_t* Hv = (f16_t*)p; p += BIG;  // total ~70MB
  f16_t* Oat_t = xc;                // alias: xc dead after Hv gemm

  f16_t* whb = w2;
  f16_t* wob = w2 + 262144;

  const long sD = (long)4096 * 512;

  stats_k<<<2048, 256, 0, stream>>>(x, mu, rs);
  wcast2_k<<<512, 256, 0, stream>>>(hw, ow, w2);
  mt_k<<<dim3(8, 8), 256, 0, stream>>>(fw, gw, Mh);
  v_k<<<2, 256, 0, stream>>>(gw, fb, vv);
  normt_k<<<dim3(64, 8, 4), 256, 0, stream>>>(x, mu, rs, xf, xc);
  u_k<<<dim3(1024, 4), 256, 0, stream>>>(vv, xf, uu);
  // Z[b][n][j] = sum_i xf[n][i] * Mh[j][i]
  gemm_k<f16_t, 0, false><<<dim3(4, 32, 4), 256, 0, stream>>>(
      xf, Mh, Zf, nullptr, nullptr, nullptr, sD, 0, sD, 512);
  // Hv[b][c][n] = h_w . xc  (+h_b over c)
  gemm_k<f16_t, 1, false><<<dim3(32, 4, 4), 256, 0, stream>>>(
      whb, xc, Hv, hb, nullptr, nullptr, 0, sD, sD, 4096);
  // attention (256 blocks, 512 threads) -> Oat_t[b][q][c]
  flash_k<<<256, 512, 0, stream>>>(Zf, xf, uu, Hv, Oat_t);
  // out[b][o][n] = o_w . Oat_t^T (+o_b over o) + residual, fp32
  gemm_k<float, 1, true><<<dim3(32, 4, 4), 256, 0, stream>>>(
      wob, Oat_t, out, ob, nullptr, x, 0, sD, sD, 4096);

  (void)in_sizes; (void)n_in; (void)out_size; (void)ws_size;
}